// Round 3
// baseline (2704.130 us; speedup 1.0000x reference)
//
#include <hip/hip_runtime.h>

#define NN 20000
#define EE 120000
#define BB 4
#define CH 256

typedef unsigned int uint;
typedef unsigned short ushort;

typedef __attribute__((ext_vector_type(8))) short bf16x8_t;
typedef __attribute__((ext_vector_type(4))) float f32x4;

__device__ __forceinline__ float bf2f(ushort h) {
    union { uint u; float f; } v; v.u = ((uint)h) << 16; return v.f;
}
__device__ __forceinline__ ushort f2bf(float f) {
    union { float f; uint u; } v; v.f = f;
    uint u = v.u;
    uint r = (u + 0x7fffu + ((u >> 16) & 1u)) >> 16;
    return (ushort)r;
}

// ---------------- CSR build ----------------

__global__ __launch_bounds__(256) void init_zero_kernel(int* cnt, int* fill) {
    int i = blockIdx.x * 256 + threadIdx.x;
    if (i < BB * NN) { cnt[i] = 0; fill[i] = 0; }
}

__global__ __launch_bounds__(256) void count_kernel(const int* __restrict__ edge, int* cnt) {
    int i = blockIdx.x * 256 + threadIdx.x;
    if (i >= BB * EE) return;
    int b = i / EE, e = i - b * EE;
    int dst = edge[(size_t)b * 2 * EE + EE + e];
    atomicAdd(&cnt[b * NN + dst], 1);
}

__global__ __launch_bounds__(256) void dinv_kernel(const int* __restrict__ cnt, float* dinv) {
    int i = blockIdx.x * 256 + threadIdx.x;
    if (i < BB * NN) dinv[i] = rsqrtf((float)(cnt[i] + 1));
}

// flatten symm to global row index: symg[b*NN+n] = b*NN + symm[b*NN+n]
__global__ __launch_bounds__(256) void symg_kernel(const int* __restrict__ symm,
                                                   int* __restrict__ symg) {
    int i = blockIdx.x * 256 + threadIdx.x;
    if (i >= BB * NN) return;
    int b = i / NN;
    symg[i] = b * NN + symm[i];
}

__global__ __launch_bounds__(256) void scan_kernel(const int* __restrict__ cnt, int* rowptr) {
    int b = blockIdx.x;
    int t = threadIdx.x;
    int lane = t & 63, wv = t >> 6;
    __shared__ int wsum[4];
    int carry = 0;
    for (int base = 0; base < NN; base += 256) {
        int v = (base + t < NN) ? cnt[b * NN + base + t] : 0;
        int incl = v;
        #pragma unroll
        for (int off = 1; off < 64; off <<= 1) {
            int u = __shfl_up(incl, off, 64);
            if (lane >= off) incl += u;
        }
        if (lane == 63) wsum[wv] = incl;
        __syncthreads();
        int wadd = 0;
        for (int w2 = 0; w2 < wv; w2++) wadd += wsum[w2];
        int tot = wsum[0] + wsum[1] + wsum[2] + wsum[3];
        if (base + t < NN) rowptr[(size_t)b * (NN + 1) + base + t] = carry + wadd + incl - v;
        carry += tot;
        __syncthreads();
    }
    if (t == 0) rowptr[(size_t)b * (NN + 1) + NN] = carry;
}

// fill packed edge records: edgew[pos] = {src, bits(dinv[src]*dinv[dst])}
__global__ __launch_bounds__(256) void fill_kernel(const int* __restrict__ edge,
                                                   const int* __restrict__ rowptr,
                                                   const float* __restrict__ dinv,
                                                   int* fill, int2* edgew) {
    int i = blockIdx.x * 256 + threadIdx.x;
    if (i >= BB * EE) return;
    int b = i / EE, e = i - b * EE;
    int src = edge[(size_t)b * 2 * EE + e];
    int dst = edge[(size_t)b * 2 * EE + EE + e];
    int pos = rowptr[(size_t)b * (NN + 1) + dst] + atomicAdd(&fill[b * NN + dst], 1);
    float w = dinv[b * NN + src] * dinv[b * NN + dst];
    edgew[(size_t)b * EE + pos] = make_int2(src, __float_as_int(w));
}

// ---------------- weight prep (float32 -> bf16) ----------------

__global__ __launch_bounds__(256) void wt_sq_kernel(const float* __restrict__ src,
                                                    ushort* __restrict__ dst) {
    int i = blockIdx.x * 256 + threadIdx.x;
    if (i >= 65536) return;
    int n = i >> 8, k = i & 255;
    dst[i] = f2bf(src[(k << 8) + n]);
}

// concat [W;Ws] per layer: dst bf16 [12][256 n][512 k]
__global__ __launch_bounds__(256) void wt_cat_kernel(const float* __restrict__ W,
                                                     const float* __restrict__ Ws,
                                                     ushort* __restrict__ dst) {
    int i = blockIdx.x * 256 + threadIdx.x;
    if (i >= 12 * 256 * 512) return;
    int mat = i >> 17;
    int rem = i & 131071;
    int n = rem >> 9, k = rem & 511;
    float v = (k < 256) ? W[(mat << 16) + (k << 8) + n]
                        : Ws[(mat << 16) + ((k - 256) << 8) + n];
    dst[i] = f2bf(v);
}

// src float [963][256] -> dst bf16 [256][1024] (zero-padded K)
__global__ __launch_bounds__(256) void wt_lin_kernel(const float* __restrict__ src,
                                                     ushort* __restrict__ dst) {
    int i = blockIdx.x * 256 + threadIdx.x;
    if (i >= 256 * 1024) return;
    int n = i >> 10, k = i & 1023;
    dst[i] = (k < 963) ? f2bf(src[k * 256 + n]) : (ushort)0;
}

// x float [80000][963] -> xp bf16 [80000][1024] zero-padded
__global__ __launch_bounds__(256) void pad_x_kernel(const float* __restrict__ x,
                                                    ushort* __restrict__ xp) {
    size_t i = (size_t)blockIdx.x * 256 + threadIdx.x;
    if (i >= (size_t)BB * NN * 1024) return;
    size_t row = i >> 10;
    int k = (int)(i & 1023);
    xp[i] = (k < 963) ? f2bf(x[row * 963 + k]) : (ushort)0;
}

// ---------------- gather: us[d] = P@h (256ch, bf16) ----------------
// HALF-WAVE per dst node: 32 lanes x uint4 (16B) = 512B = one full 256ch bf16 row.
// Each wave serves 2 nodes; chunk-of-4 edges keeps 4 row-loads (64B/lane) in flight.
// packed edge records (src, weight) -> one dependent load per edge.

__device__ __forceinline__ void acc8(float* a, float w, uint4 v) {
    const uint* vp = (const uint*)&v;
    #pragma unroll
    for (int q = 0; q < 4; q++) {
        a[2 * q]     += w * bf2f((ushort)(vp[q] & 0xffff));
        a[2 * q + 1] += w * bf2f((ushort)(vp[q] >> 16));
    }
}

__global__ __launch_bounds__(256) void gather_kernel(const ushort* __restrict__ h,
                                                     const float* __restrict__ dinv,
                                                     const int* __restrict__ rowptr,
                                                     const int2* __restrict__ edgew,
                                                     ushort* __restrict__ us) {
    int t = threadIdx.x;
    int hw = t >> 5, lane32 = t & 31;
    int d = blockIdx.x * 8 + hw;
    int b = blockIdx.y;
    const ushort* hb = h + (size_t)b * NN * CH;
    int co = lane32 * 8;
    int r0 = rowptr[(size_t)b * (NN + 1) + d];
    int r1 = rowptr[(size_t)b * (NN + 1) + d + 1];
    float dd = dinv[b * NN + d];
    const int2* cw = edgew + (size_t)b * EE;
    float a[8];
    {   // self loop
        float w = dd * dd;
        uint4 v = *(const uint4*)(hb + (size_t)d * CH + co);
        const uint* vp = (const uint*)&v;
        #pragma unroll
        for (int q = 0; q < 4; q++) {
            a[2 * q]     = w * bf2f((ushort)(vp[q] & 0xffff));
            a[2 * q + 1] = w * bf2f((ushort)(vp[q] >> 16));
        }
    }
    int j = r0;
    for (; j + 4 <= r1; j += 4) {
        int2 e0 = cw[j], e1 = cw[j + 1], e2 = cw[j + 2], e3 = cw[j + 3];
        uint4 v0 = *(const uint4*)(hb + (size_t)e0.x * CH + co);
        uint4 v1 = *(const uint4*)(hb + (size_t)e1.x * CH + co);
        uint4 v2 = *(const uint4*)(hb + (size_t)e2.x * CH + co);
        uint4 v3 = *(const uint4*)(hb + (size_t)e3.x * CH + co);
        acc8(a, __int_as_float(e0.y), v0);
        acc8(a, __int_as_float(e1.y), v1);
        acc8(a, __int_as_float(e2.y), v2);
        acc8(a, __int_as_float(e3.y), v3);
    }
    for (; j < r1; j++) {
        int2 e = cw[j];
        uint4 v = *(const uint4*)(hb + (size_t)e.x * CH + co);
        acc8(a, __int_as_float(e.y), v);
    }
    uint o[4];
    #pragma unroll
    for (int q = 0; q < 4; q++)
        o[q] = (uint)f2bf(a[2 * q]) | ((uint)f2bf(a[2 * q + 1]) << 16);
    size_t orow = ((size_t)b * NN + d) * CH;
    *(uint4*)(us + orow + co) = *(const uint4*)o;
}

// ---------------- MFMA GEMM: C[M][256] = A[M][K] @ Wt^T + bias (relu) (resid avg) ----------
// 512 threads, BM=128, BN=256 (full width), BK=64. XOR-swizzled LDS (LDK=64, no pad).
// 2-phase pipeline: next K-tile's global loads issue BEFORE current tile's MFMA
// (latency hides under compute; T3 minimum recipe).
// A columns: [0,256) from A (lda stride); [256,512) (when hsym!=null) read directly from
//            hsym[symg[row]] — the symm copy is never materialized.
// Epilogue: per-wave LDS repack -> coalesced uint4 stores. resid (bf16): v=(resid+v)*0.5.

#define BM 128

__global__ __launch_bounds__(512, 4) void gemm_bf16(const ushort* __restrict__ A, int lda,
                                                    const ushort* __restrict__ Wt,
                                                    const float* __restrict__ bias,
                                                    const ushort* __restrict__ resid,
                                                    const ushort* __restrict__ hsym,
                                                    const int* __restrict__ symg,
                                                    ushort* __restrict__ outb,
                                                    int M, int K, int relu) {
    __shared__ __align__(16) ushort smem[32768];  // 64 KB: staging 48 KB; epilogue 8 KB/wave
    ushort* As = smem;            // [128][64] swizzled
    ushort* Bs = smem + 128 * 64; // [256][64] swizzled
    int t = threadIdx.x;
    int lane = t & 63, wv = t >> 6;
    int m0 = blockIdx.x * BM;
    int lm = lane & 15, quad = lane >> 4;
    int wm = (wv >> 2) * 64;   // 2 m-halves
    int wn = (wv & 3) * 64;    // 4 n-quarters

    // symm row indices for the two A-load rows this thread covers (hoisted)
    int sy0 = 0, sy1 = 0;
    if (hsym) {
        sy0 = symg[m0 + (t >> 3)];
        sy1 = symg[m0 + 64 + (t >> 3)];
    }

    f32x4 acc[4][4];
    #pragma unroll
    for (int i = 0; i < 4; i++)
        #pragma unroll
        for (int j = 0; j < 4; j++) acc[i][j] = (f32x4){0.f, 0.f, 0.f, 0.f};

    uint4 av[2], bv[4];
    auto loadA = [&](int kt) {
        #pragma unroll
        for (int p = 0; p < 2; p++) {
            int idx = p * 512 + t;
            int row = idx >> 3, ch = idx & 7;
            const ushort* srcp;
            if (hsym && kt >= 256) {
                int sy = (p == 0) ? sy0 : sy1;
                srcp = hsym + (size_t)sy * CH + (kt - 256) + ch * 8;
            } else {
                srcp = A + (size_t)(m0 + row) * lda + kt + ch * 8;
            }
            av[p] = *(const uint4*)srcp;
        }
    };
    auto loadB = [&](int kt) {
        #pragma unroll
        for (int p = 0; p < 4; p++) {
            int idx = p * 512 + t;
            int row = idx >> 3, ch = idx & 7;
            bv[p] = *(const uint4*)(Wt + (size_t)row * K + kt + ch * 8);
        }
    };

    loadA(0);
    loadB(0);
    for (int kt = 0; kt < K; kt += 64) {
        __syncthreads();  // all waves done with LDS reads of previous tile
        #pragma unroll
        for (int p = 0; p < 2; p++) {
            int idx = p * 512 + t;
            int row = idx >> 3, ch = idx & 7;
            *(uint4*)(As + row * 64 + ((ch ^ (row & 7)) << 3)) = av[p];
        }
        #pragma unroll
        for (int p = 0; p < 4; p++) {
            int idx = p * 512 + t;
            int row = idx >> 3, ch = idx & 7;
            *(uint4*)(Bs + row * 64 + ((ch ^ (row & 7)) << 3)) = bv[p];
        }
        __syncthreads();
        if (kt + 64 < K) {  // issue next tile's loads; latency hides under MFMA
            loadA(kt + 64);
            loadB(kt + 64);
        }
        #pragma unroll
        for (int ks = 0; ks < 2; ks++) {
            bf16x8_t af[4];
            #pragma unroll
            for (int i = 0; i < 4; i++) {
                int row = wm + i * 16 + lm;
                int chunk = (ks * 4 + quad) ^ (row & 7);
                af[i] = *(const bf16x8_t*)(As + row * 64 + chunk * 8);
            }
            #pragma unroll
            for (int j = 0; j < 4; j++) {
                int row = wn + j * 16 + lm;
                int chunk = (ks * 4 + quad) ^ (row & 7);
                bf16x8_t bfr = *(const bf16x8_t*)(Bs + row * 64 + chunk * 8);
                #pragma unroll
                for (int i = 0; i < 4; i++)
                    acc[i][j] = __builtin_amdgcn_mfma_f32_16x16x32_bf16(af[i], bfr, acc[i][j], 0, 0, 0);
            }
        }
    }

    // ---- epilogue ----
    float bj[4];
    #pragma unroll
    for (int j = 0; j < 4; j++) bj[j] = bias[wn + j * 16 + lm];
    __syncthreads();  // all waves done reading As/Bs before eb overwrite
    ushort* eb = smem + wv * 4096;  // 64 rows x 64 cols, chunk-swizzled by row&7
    #pragma unroll
    for (int i = 0; i < 4; i++) {
        #pragma unroll
        for (int r = 0; r < 4; r++) {
            int row = i * 16 + quad * 4 + r;  // 0..63
            int sw = row & 7;
            #pragma unroll
            for (int j = 0; j < 4; j++) {
                int col = j * 16 + lm;
                int scol = ((((col >> 3) ^ sw)) << 3) | (col & 7);
                float v = acc[i][j][r] + bj[j];
                if (relu) v = fmaxf(v, 0.f);
                eb[row * 64 + scol] = f2bf(v);
            }
        }
    }
    // wave-local readback + coalesced store (8 rows x 128B full lines per instr)
    int rl = lane >> 3, c8 = lane & 7;
    #pragma unroll
    for (int s = 0; s < 8; s++) {
        int row = s * 8 + rl;  // 0..63
        int chunk = c8 ^ (row & 7);
        uint4 v = *(const uint4*)(eb + row * 64 + chunk * 8);
        size_t ga = (size_t)(m0 + wm + row) * CH + wn + c8 * 8;
        if (resid) {
            uint4 h = *(const uint4*)(resid + ga);
            uint res[4];
            const uint* vp = (const uint*)&v;
            const uint* hp = (const uint*)&h;
            #pragma unroll
            for (int w = 0; w < 4; w++) {
                float y0 = bf2f((ushort)(vp[w] & 0xffff));
                float y1 = bf2f((ushort)(vp[w] >> 16));
                float h0 = bf2f((ushort)(hp[w] & 0xffff));
                float h1 = bf2f((ushort)(hp[w] >> 16));
                res[w] = (uint)f2bf((h0 + y0) * 0.5f) | ((uint)f2bf((h1 + y1) * 0.5f) << 16);
            }
            v = *(uint4*)res;
        }
        *(uint4*)(outb + ga) = v;
    }
}

// ---------------- fused: h (bf16) -> output 0 (fp32)  AND  h @ W3 -> t3 ----------------

__global__ __launch_bounds__(256) void cvt3_kernel(const ushort* __restrict__ Hb,
                                                   const float* __restrict__ W3,
                                                   float* __restrict__ Hf,
                                                   float* __restrict__ t3) {
    int wv = threadIdx.x >> 6, lane = threadIdx.x & 63;
    int nd = blockIdx.x * 4 + wv;  // [0, BB*NN)
    uint2 hv = *(const uint2*)(Hb + (size_t)nd * CH + lane * 4);
    float hp[4];
    hp[0] = bf2f((ushort)(hv.x & 0xffff));
    hp[1] = bf2f((ushort)(hv.x >> 16));
    hp[2] = bf2f((ushort)(hv.y & 0xffff));
    hp[3] = bf2f((ushort)(hv.y >> 16));
    float4 o;
    o.x = hp[0]; o.y = hp[1]; o.z = hp[2]; o.w = hp[3];
    *(float4*)(Hf + (size_t)nd * CH + lane * 4) = o;
    int k0 = lane * 4;
    float s0 = 0.f, s1 = 0.f, s2 = 0.f;
    #pragma unroll
    for (int j = 0; j < 4; j++) {
        float h = hp[j];
        s0 += h * W3[(k0 + j) * 3 + 0];
        s1 += h * W3[(k0 + j) * 3 + 1];
        s2 += h * W3[(k0 + j) * 3 + 2];
    }
    #pragma unroll
    for (int off = 32; off; off >>= 1) {
        s0 += __shfl_down(s0, off, 64);
        s1 += __shfl_down(s1, off, 64);
        s2 += __shfl_down(s2, off, 64);
    }
    if (lane == 0) {
        t3[(size_t)nd * 3 + 0] = s0;
        t3[(size_t)nd * 3 + 1] = s1;
        t3[(size_t)nd * 3 + 2] = s2;
    }
}

__global__ __launch_bounds__(256) void agg3_kernel(const float* __restrict__ t3,
                                                   const float* __restrict__ bias,
                                                   const float* __restrict__ dinv,
                                                   const int* __restrict__ rowptr,
                                                   const int2* __restrict__ edgew,
                                                   float* __restrict__ out) {
    int i = blockIdx.x * 256 + threadIdx.x;
    if (i >= BB * NN) return;
    int b = i / NN, d = i - b * NN;
    const float* t3b = t3 + (size_t)b * NN * 3;
    int r0 = rowptr[(size_t)b * (NN + 1) + d];
    int r1 = rowptr[(size_t)b * (NN + 1) + d + 1];
    float dd = dinv[b * NN + d];
    float a0 = 0.f, a1 = 0.f, a2 = 0.f;
    const int2* cw = edgew + (size_t)b * EE;
    for (int j = r0; j < r1; j++) {
        int2 e = cw[j];
        float w = __int_as_float(e.y);
        a0 += w * t3b[e.x * 3 + 0];
        a1 += w * t3b[e.x * 3 + 1];
        a2 += w * t3b[e.x * 3 + 2];
    }
    float w = dd * dd;
    a0 += w * t3b[d * 3 + 0] + bias[0];
    a1 += w * t3b[d * 3 + 1] + bias[1];
    a2 += w * t3b[d * 3 + 2] + bias[2];
    size_t o = (size_t)i * 3;
    out[o + 0] = a0;
    out[o + 1] = a1;
    out[o + 2] = a2;
}

// ---------------- host ----------------

extern "C" void kernel_launch(void* const* d_in, const int* in_sizes, int n_in,
                              void* d_out, int out_size, void* d_ws, size_t ws_size,
                              hipStream_t stream) {
    const float* x     = (const float*)d_in[0];
    const int*   edge  = (const int*)d_in[1];
    const int*   symm  = (const int*)d_in[2];
    const float* linW  = (const float*)d_in[3];
    const float* linb  = (const float*)d_in[4];
    const float* c1W   = (const float*)d_in[5];
    const float* c1b   = (const float*)d_in[6];
    const float* blkW  = (const float*)d_in[7];
    const float* blkWs = (const float*)d_in[8];
    const float* blkb  = (const float*)d_in[9];
    const float* c3W   = (const float*)d_in[10];
    const float* c3b   = (const float*)d_in[11];

    char* ws = (char*)d_ws;
    size_t off = 0;
    auto alloc = [&](size_t bytes) -> void* {
        void* p = ws + off;
        off += (bytes + 255) & ~(size_t)255;
        return p;
    };
    ushort* xp     = (ushort*)alloc((size_t)BB * NN * 1024 * 2);  // 164 MB; us aliases after lin
    ushort* us     = xp;                                          // [B*N][256] bf16 (41 MB)
    ushort* Hb     = (ushort*)alloc((size_t)BB * NN * CH * 2);
    ushort* y      = (ushort*)alloc((size_t)BB * NN * CH * 2);
    float*  t3     = (float*) alloc((size_t)BB * NN * 3 * 4);
    ushort* linWt  = (ushort*)alloc((size_t)256 * 1024 * 2);
    ushort* c1Wt   = (ushort*)alloc((size_t)256 * 256 * 2);
    ushort* blkWc  = (ushort*)alloc((size_t)12 * 256 * 512 * 2);
    int*    cnt    = (int*)  alloc((size_t)BB * NN * 4);
    int*    fill   = (int*)  alloc((size_t)BB * NN * 4);
    float*  dinv   = (float*)alloc((size_t)BB * NN * 4);
    int*    rowptr = (int*)  alloc((size_t)BB * (NN + 1) * 4);
    int2*   edgew  = (int2*) alloc((size_t)BB * EE * 8);
    int*    symg   = (int*)  alloc((size_t)BB * NN * 4);

    float* Hf   = (float*)d_out;                  // [B,N,256] float (output 0 = final h)
    float* out2 = Hf + (size_t)BB * NN * CH;      // [B,N,3] float (output 1)

    // CSR + norm
    init_zero_kernel<<<(BB * NN + 255) / 256, 256, 0, stream>>>(cnt, fill);
    count_kernel<<<(BB * EE + 255) / 256, 256, 0, stream>>>(edge, cnt);
    dinv_kernel<<<(BB * NN + 255) / 256, 256, 0, stream>>>(cnt, dinv);
    symg_kernel<<<(BB * NN + 255) / 256, 256, 0, stream>>>(symm, symg);
    scan_kernel<<<BB, 256, 0, stream>>>(cnt, rowptr);
    fill_kernel<<<(BB * EE + 255) / 256, 256, 0, stream>>>(edge, rowptr, dinv, fill, edgew);

    // weight conversion/transpose (float -> bf16)
    wt_lin_kernel<<<(256 * 1024 + 255) / 256, 256, 0, stream>>>(linW, linWt);
    wt_sq_kernel<<<(65536 + 255) / 256, 256, 0, stream>>>(c1W, c1Wt);
    wt_cat_kernel<<<(12 * 256 * 512 + 255) / 256, 256, 0, stream>>>(blkW, blkWs, blkWc);

    int ggrid = (BB * NN) / BM;     // 625 blocks, full N=256 per block
    dim3 agrid(NN / 8, BB);         // 2500 x 4, 8 nodes/block (half-wave each)

    // lin: pad+convert all batches, one GEMM (K=1024) -> Hb (bf16)
    pad_x_kernel<<<(int)(((size_t)BB * NN * 1024 + 255) / 256), 256, 0, stream>>>(x, xp);
    gemm_bf16<<<ggrid, 512, 0, stream>>>(xp, 1024, linWt, linb, nullptr, nullptr, nullptr,
                                         Hb, BB * NN, 1024, 0);

    // conv1: u = P@x_lin; h = relu(u@c1W + c1b) -> Hb
    gather_kernel<<<agrid, 256, 0, stream>>>(Hb, dinv, rowptr, edgew, us);
    gemm_bf16<<<ggrid, 512, 0, stream>>>(us, 256, c1Wt, c1b, nullptr, nullptr, nullptr,
                                         Hb, BB * NN, 256, 1);

    // 6 GBottleneck blocks: y = relu([P@h|h[symm]]@Wc0 + b0);
    //                       h = (h + relu([P@y|y[symm]]@Wc1 + b1)) * 0.5
    // symm half read directly inside the GEMM (hsym + symg), never materialized.
    for (int i = 0; i < 6; i++) {
        const ushort* Wc0 = blkWc + (size_t)(2 * i) * 131072;
        const float*  b0  = blkb  + (size_t)(2 * i) * 256;
        const ushort* Wc1 = blkWc + (size_t)(2 * i + 1) * 131072;
        const float*  b1  = blkb  + (size_t)(2 * i + 1) * 256;

        gather_kernel<<<agrid, 256, 0, stream>>>(Hb, dinv, rowptr, edgew, us);
        gemm_bf16<<<ggrid, 512, 0, stream>>>(us, 256, Wc0, b0, nullptr, Hb, symg,
                                             y, BB * NN, 512, 1);

        gather_kernel<<<agrid, 256, 0, stream>>>(y, dinv, rowptr, edgew, us);
        gemm_bf16<<<ggrid, 512, 0, stream>>>(us, 256, Wc1, b1, Hb, y, symg,
                                             Hb, BB * NN, 512, 1);
    }

    // output 0 (h fp32) + conv3 projection, single pass over Hb
    cvt3_kernel<<<(BB * NN) / 4, 256, 0, stream>>>(Hb, c3W, Hf, t3);
    agg3_kernel<<<(BB * NN + 255) / 256, 256, 0, stream>>>(t3, c3b, dinv,
                                                           rowptr, edgew, out2);

    (void)in_sizes; (void)n_in; (void)out_size; (void)ws_size;
}

// Round 7
// 1751.617 us; speedup vs baseline: 1.5438x; 1.5438x over previous
//
#include <hip/hip_runtime.h>

#define NN 20000
#define EE 120000
#define BB 4
#define CH 256

typedef unsigned int uint;
typedef unsigned short ushort;

typedef __attribute__((ext_vector_type(8))) short bf16x8_t;
typedef __attribute__((ext_vector_type(4))) float f32x4;

__device__ __forceinline__ float bf2f(ushort h) {
    union { uint u; float f; } v; v.u = ((uint)h) << 16; return v.f;
}
__device__ __forceinline__ ushort f2bf(float f) {
    union { float f; uint u; } v; v.f = f;
    uint u = v.u;
    uint r = (u + 0x7fffu + ((u >> 16) & 1u)) >> 16;
    return (ushort)r;
}

// direct global->LDS copy, 16B per lane; LDS dest must be wave-uniform base + lane*16
__device__ __forceinline__ void gload_lds16(const ushort* g, ushort* l) {
    __builtin_amdgcn_global_load_lds((const __attribute__((address_space(1))) void*)g,
                                     (__attribute__((address_space(3))) void*)l, 16, 0, 0);
}

// ---------------- CSR build ----------------

__global__ __launch_bounds__(256) void init_zero_kernel(int* cnt, int* fill) {
    int i = blockIdx.x * 256 + threadIdx.x;
    if (i < BB * NN) { cnt[i] = 0; fill[i] = 0; }
}

__global__ __launch_bounds__(256) void count_kernel(const int* __restrict__ edge, int* cnt) {
    int i = blockIdx.x * 256 + threadIdx.x;
    if (i >= BB * EE) return;
    int b = i / EE, e = i - b * EE;
    int dst = edge[(size_t)b * 2 * EE + EE + e];
    atomicAdd(&cnt[b * NN + dst], 1);
}

__global__ __launch_bounds__(256) void dinv_kernel(const int* __restrict__ cnt, float* dinv) {
    int i = blockIdx.x * 256 + threadIdx.x;
    if (i < BB * NN) dinv[i] = rsqrtf((float)(cnt[i] + 1));
}

// flatten symm to global row index: symg[b*NN+n] = b*NN + symm[b*NN+n]
__global__ __launch_bounds__(256) void symg_kernel(const int* __restrict__ symm,
                                                   int* __restrict__ symg) {
    int i = blockIdx.x * 256 + threadIdx.x;
    if (i >= BB * NN) return;
    int b = i / NN;
    symg[i] = b * NN + symm[i];
}

__global__ __launch_bounds__(256) void scan_kernel(const int* __restrict__ cnt, int* rowptr) {
    int b = blockIdx.x;
    int t = threadIdx.x;
    int lane = t & 63, wv = t >> 6;
    __shared__ int wsum[4];
    int carry = 0;
    for (int base = 0; base < NN; base += 256) {
        int v = (base + t < NN) ? cnt[b * NN + base + t] : 0;
        int incl = v;
        #pragma unroll
        for (int off = 1; off < 64; off <<= 1) {
            int u = __shfl_up(incl, off, 64);
            if (lane >= off) incl += u;
        }
        if (lane == 63) wsum[wv] = incl;
        __syncthreads();
        int wadd = 0;
        for (int w2 = 0; w2 < wv; w2++) wadd += wsum[w2];
        int tot = wsum[0] + wsum[1] + wsum[2] + wsum[3];
        if (base + t < NN) rowptr[(size_t)b * (NN + 1) + base + t] = carry + wadd + incl - v;
        carry += tot;
        __syncthreads();
    }
    if (t == 0) rowptr[(size_t)b * (NN + 1) + NN] = carry;
}

// fill packed edge records: edgew[pos] = {src, bits(dinv[src]*dinv[dst])}
__global__ __launch_bounds__(256) void fill_kernel(const int* __restrict__ edge,
                                                   const int* __restrict__ rowptr,
                                                   const float* __restrict__ dinv,
                                                   int* fill, int2* edgew) {
    int i = blockIdx.x * 256 + threadIdx.x;
    if (i >= BB * EE) return;
    int b = i / EE, e = i - b * EE;
    int src = edge[(size_t)b * 2 * EE + e];
    int dst = edge[(size_t)b * 2 * EE + EE + e];
    int pos = rowptr[(size_t)b * (NN + 1) + dst] + atomicAdd(&fill[b * NN + dst], 1);
    float w = dinv[b * NN + src] * dinv[b * NN + dst];
    edgew[(size_t)b * EE + pos] = make_int2(src, __float_as_int(w));
}

// ---------------- weight prep (float32 -> bf16) ----------------

__global__ __launch_bounds__(256) void wt_sq_kernel(const float* __restrict__ src,
                                                    ushort* __restrict__ dst) {
    int i = blockIdx.x * 256 + threadIdx.x;
    if (i >= 65536) return;
    int n = i >> 8, k = i & 255;
    dst[i] = f2bf(src[(k << 8) + n]);
}

// concat [W;Ws] per layer: dst bf16 [12][256 n][512 k]
__global__ __launch_bounds__(256) void wt_cat_kernel(const float* __restrict__ W,
                                                     const float* __restrict__ Ws,
                                                     ushort* __restrict__ dst) {
    int i = blockIdx.x * 256 + threadIdx.x;
    if (i >= 12 * 256 * 512) return;
    int mat = i >> 17;
    int rem = i & 131071;
    int n = rem >> 9, k = rem & 511;
    float v = (k < 256) ? W[(mat << 16) + (k << 8) + n]
                        : Ws[(mat << 16) + ((k - 256) << 8) + n];
    dst[i] = f2bf(v);
}

// src float [963][256] -> dst bf16 [256][1024] (zero-padded K)
__global__ __launch_bounds__(256) void wt_lin_kernel(const float* __restrict__ src,
                                                     ushort* __restrict__ dst) {
    int i = blockIdx.x * 256 + threadIdx.x;
    if (i >= 256 * 1024) return;
    int n = i >> 10, k = i & 1023;
    dst[i] = (k < 963) ? f2bf(src[k * 256 + n]) : (ushort)0;
}

// x float [80000][963] -> xp bf16 [80000][1024] zero-padded
__global__ __launch_bounds__(256) void pad_x_kernel(const float* __restrict__ x,
                                                    ushort* __restrict__ xp) {
    size_t i = (size_t)blockIdx.x * 256 + threadIdx.x;
    if (i >= (size_t)BB * NN * 1024) return;
    size_t row = i >> 10;
    int k = (int)(i & 1023);
    xp[i] = (k < 963) ? f2bf(x[row * 963 + k]) : (ushort)0;
}

// ---------------- gather: us[d] = P@h (256ch, bf16) ----------------
// HALF-WAVE per dst node: 32 lanes x uint4 (16B) = 512B = one full 256ch bf16 row.
// Each wave serves 2 nodes; chunk-of-4 edges keeps 4 row-loads (64B/lane) in flight.
// packed edge records (src, weight) -> one dependent load per edge.

__device__ __forceinline__ void acc8(float* a, float w, uint4 v) {
    const uint* vp = (const uint*)&v;
    #pragma unroll
    for (int q = 0; q < 4; q++) {
        a[2 * q]     += w * bf2f((ushort)(vp[q] & 0xffff));
        a[2 * q + 1] += w * bf2f((ushort)(vp[q] >> 16));
    }
}

__global__ __launch_bounds__(256) void gather_kernel(const ushort* __restrict__ h,
                                                     const float* __restrict__ dinv,
                                                     const int* __restrict__ rowptr,
                                                     const int2* __restrict__ edgew,
                                                     ushort* __restrict__ us) {
    int t = threadIdx.x;
    int hw = t >> 5, lane32 = t & 31;
    int d = blockIdx.x * 8 + hw;
    int b = blockIdx.y;
    const ushort* hb = h + (size_t)b * NN * CH;
    int co = lane32 * 8;
    int r0 = rowptr[(size_t)b * (NN + 1) + d];
    int r1 = rowptr[(size_t)b * (NN + 1) + d + 1];
    float dd = dinv[b * NN + d];
    const int2* cw = edgew + (size_t)b * EE;
    float a[8];
    {   // self loop
        float w = dd * dd;
        uint4 v = *(const uint4*)(hb + (size_t)d * CH + co);
        const uint* vp = (const uint*)&v;
        #pragma unroll
        for (int q = 0; q < 4; q++) {
            a[2 * q]     = w * bf2f((ushort)(vp[q] & 0xffff));
            a[2 * q + 1] = w * bf2f((ushort)(vp[q] >> 16));
        }
    }
    int j = r0;
    for (; j + 4 <= r1; j += 4) {
        int2 e0 = cw[j], e1 = cw[j + 1], e2 = cw[j + 2], e3 = cw[j + 3];
        uint4 v0 = *(const uint4*)(hb + (size_t)e0.x * CH + co);
        uint4 v1 = *(const uint4*)(hb + (size_t)e1.x * CH + co);
        uint4 v2 = *(const uint4*)(hb + (size_t)e2.x * CH + co);
        uint4 v3 = *(const uint4*)(hb + (size_t)e3.x * CH + co);
        acc8(a, __int_as_float(e0.y), v0);
        acc8(a, __int_as_float(e1.y), v1);
        acc8(a, __int_as_float(e2.y), v2);
        acc8(a, __int_as_float(e3.y), v3);
    }
    for (; j < r1; j++) {
        int2 e = cw[j];
        uint4 v = *(const uint4*)(hb + (size_t)e.x * CH + co);
        acc8(a, __int_as_float(e.y), v);
    }
    uint o[4];
    #pragma unroll
    for (int q = 0; q < 4; q++)
        o[q] = (uint)f2bf(a[2 * q]) | ((uint)f2bf(a[2 * q + 1]) << 16);
    size_t orow = ((size_t)b * NN + d) * CH;
    *(uint4*)(us + orow + co) = *(const uint4*)o;
}

// ---------------- MFMA GEMM: C[M][256] = A[M][K] @ Wt^T + bias (relu) (resid avg) ----------
// 512 threads, BM=128, BN=256 (full width), BK=64. XOR-swizzled LDS (LDK=64, no pad).
// Staging via global_load_lds (16B/lane, direct to LDS): no staging VGPRs -> no spill at
// 2 blocks/CU (launch_bounds 512,4: 128 unified regs/wave; acc=64 AGPR + ~45 VGPR fits).
// Swizzle achieved by PRE-SWIZZLING the per-lane GLOBAL source chunk (ch ^ (row&7));
// LDS dest stays linear (base + lane*16) as HW requires. Reader layout unchanged.
// A columns: [0,256) from A (lda stride); [256,512) (when hsym!=null) read directly from
//            hsym[symg[row]] — the symm copy is never materialized.
// Epilogue: per-wave LDS repack -> coalesced uint4 stores. resid (bf16): v=(resid+v)*0.5.

#define BM 128

__global__ __launch_bounds__(512, 4) void gemm_bf16(const ushort* __restrict__ A, int lda,
                                                    const ushort* __restrict__ Wt,
                                                    const float* __restrict__ bias,
                                                    const ushort* __restrict__ resid,
                                                    const ushort* __restrict__ hsym,
                                                    const int* __restrict__ symg,
                                                    ushort* __restrict__ outb,
                                                    int M, int K, int relu) {
    __shared__ __align__(16) ushort smem[32768];  // 64 KB: staging 48 KB; epilogue 8 KB/wave
    ushort* As = smem;            // [128][64] swizzled
    ushort* Bs = smem + 128 * 64; // [256][64] swizzled
    int t = threadIdx.x;
    int lane = t & 63, wv = t >> 6;
    int m0 = blockIdx.x * BM;
    int lm = lane & 15, quad = lane >> 4;
    int wm = (wv >> 2) * 64;   // 2 m-halves
    int wn = (wv & 3) * 64;    // 4 n-quarters

    // staging geometry: thread t covers row = p*64 + (t>>3), global chunk (t&7)^(srow&7)
    int srow = t >> 3, sch = t & 7;
    int gch = sch ^ (srow & 7);          // p*64 doesn't change row&7

    const ushort* aP[2];   // A source (swizzle baked in)
    const ushort* sP[2];   // hsym source (pre-shifted by -256 so +kt works)
    ushort* aL[2];         // linear LDS dest
    #pragma unroll
    for (int p = 0; p < 2; p++) {
        int row = p * 64 + srow;
        aP[p] = A + (size_t)(m0 + row) * lda + gch * 8;
        aL[p] = As + (p * 512 + t) * 8;
        sP[p] = aP[p];
    }
    if (hsym) {
        #pragma unroll
        for (int p = 0; p < 2; p++) {
            int sy = symg[m0 + p * 64 + srow];
            sP[p] = hsym + (size_t)sy * CH - 256 + gch * 8;
        }
    }
    const ushort* bP[4];
    ushort* bL[4];
    #pragma unroll
    for (int p = 0; p < 4; p++) {
        int row = p * 64 + srow;
        bP[p] = Wt + (size_t)row * K + gch * 8;
        bL[p] = Bs + (p * 512 + t) * 8;
    }

    f32x4 acc[4][4];
    #pragma unroll
    for (int i = 0; i < 4; i++)
        #pragma unroll
        for (int j = 0; j < 4; j++) acc[i][j] = (f32x4){0.f, 0.f, 0.f, 0.f};

    for (int kt = 0; kt < K; kt += 64) {
        __syncthreads();  // all waves done reading LDS from previous tile
        bool useSym = hsym && (kt >= 256);
        #pragma unroll
        for (int p = 0; p < 2; p++)
            gload_lds16((useSym ? sP[p] : aP[p]) + kt, aL[p]);
        #pragma unroll
        for (int p = 0; p < 4; p++)
            gload_lds16(bP[p] + kt, bL[p]);
        __syncthreads();  // vmcnt(0) drain at barrier: LDS tile ready
        #pragma unroll
        for (int ks = 0; ks < 2; ks++) {
            bf16x8_t af[4];
            #pragma unroll
            for (int i = 0; i < 4; i++) {
                int row = wm + i * 16 + lm;
                int chunk = (ks * 4 + quad) ^ (row & 7);
                af[i] = *(const bf16x8_t*)(As + row * 64 + chunk * 8);
            }
            #pragma unroll
            for (int j = 0; j < 4; j++) {
                int row = wn + j * 16 + lm;
                int chunk = (ks * 4 + quad) ^ (row & 7);
                bf16x8_t bfr = *(const bf16x8_t*)(Bs + row * 64 + chunk * 8);
                #pragma unroll
                for (int i = 0; i < 4; i++)
                    acc[i][j] = __builtin_amdgcn_mfma_f32_16x16x32_bf16(af[i], bfr, acc[i][j], 0, 0, 0);
            }
        }
    }

    // ---- epilogue ----
    float bj[4];
    #pragma unroll
    for (int j = 0; j < 4; j++) bj[j] = bias[wn + j * 16 + lm];
    __syncthreads();  // all waves done reading As/Bs before eb overwrite
    ushort* eb = smem + wv * 4096;  // 64 rows x 64 cols, chunk-swizzled by row&7
    #pragma unroll
    for (int i = 0; i < 4; i++) {
        #pragma unroll
        for (int r = 0; r < 4; r++) {
            int row = i * 16 + quad * 4 + r;  // 0..63
            int sw = row & 7;
            #pragma unroll
            for (int j = 0; j < 4; j++) {
                int col = j * 16 + lm;
                int scol = ((((col >> 3) ^ sw)) << 3) | (col & 7);
                float v = acc[i][j][r] + bj[j];
                if (relu) v = fmaxf(v, 0.f);
                eb[row * 64 + scol] = f2bf(v);
            }
        }
    }
    // wave-local readback + coalesced store (8 rows x 128B full lines per instr)
    int rl = lane >> 3, c8 = lane & 7;
    #pragma unroll
    for (int s = 0; s < 8; s++) {
        int row = s * 8 + rl;  // 0..63
        int chunk = c8 ^ (row & 7);
        uint4 v = *(const uint4*)(eb + row * 64 + chunk * 8);
        size_t ga = (size_t)(m0 + wm + row) * CH + wn + c8 * 8;
        if (resid) {
            uint4 h = *(const uint4*)(resid + ga);
            uint res[4];
            const uint* vp = (const uint*)&v;
            const uint* hp = (const uint*)&h;
            #pragma unroll
            for (int w = 0; w < 4; w++) {
                float y0 = bf2f((ushort)(vp[w] & 0xffff));
                float y1 = bf2f((ushort)(vp[w] >> 16));
                float h0 = bf2f((ushort)(hp[w] & 0xffff));
                float h1 = bf2f((ushort)(hp[w] >> 16));
                res[w] = (uint)f2bf((h0 + y0) * 0.5f) | ((uint)f2bf((h1 + y1) * 0.5f) << 16);
            }
            v = *(uint4*)res;
        }
        *(uint4*)(outb + ga) = v;
    }
}

// ---------------- fused: h (bf16) -> output 0 (fp32)  AND  h @ W3 -> t3 ----------------

__global__ __launch_bounds__(256) void cvt3_kernel(const ushort* __restrict__ Hb,
                                                   const float* __restrict__ W3,
                                                   float* __restrict__ Hf,
                                                   float* __restrict__ t3) {
    int wv = threadIdx.x >> 6, lane = threadIdx.x & 63;
    int nd = blockIdx.x * 4 + wv;  // [0, BB*NN)
    uint2 hv = *(const uint2*)(Hb + (size_t)nd * CH + lane * 4);
    float hp[4];
    hp[0] = bf2f((ushort)(hv.x & 0xffff));
    hp[1] = bf2f((ushort)(hv.x >> 16));
    hp[2] = bf2f((ushort)(hv.y & 0xffff));
    hp[3] = bf2f((ushort)(hv.y >> 16));
    float4 o;
    o.x = hp[0]; o.y = hp[1]; o.z = hp[2]; o.w = hp[3];
    *(float4*)(Hf + (size_t)nd * CH + lane * 4) = o;
    int k0 = lane * 4;
    float s0 = 0.f, s1 = 0.f, s2 = 0.f;
    #pragma unroll
    for (int j = 0; j < 4; j++) {
        float h = hp[j];
        s0 += h * W3[(k0 + j) * 3 + 0];
        s1 += h * W3[(k0 + j) * 3 + 1];
        s2 += h * W3[(k0 + j) * 3 + 2];
    }
    #pragma unroll
    for (int off = 32; off; off >>= 1) {
        s0 += __shfl_down(s0, off, 64);
        s1 += __shfl_down(s1, off, 64);
        s2 += __shfl_down(s2, off, 64);
    }
    if (lane == 0) {
        t3[(size_t)nd * 3 + 0] = s0;
        t3[(size_t)nd * 3 + 1] = s1;
        t3[(size_t)nd * 3 + 2] = s2;
    }
}

__global__ __launch_bounds__(256) void agg3_kernel(const float* __restrict__ t3,
                                                   const float* __restrict__ bias,
                                                   const float* __restrict__ dinv,
                                                   const int* __restrict__ rowptr,
                                                   const int2* __restrict__ edgew,
                                                   float* __restrict__ out) {
    int i = blockIdx.x * 256 + threadIdx.x;
    if (i >= BB * NN) return;
    int b = i / NN, d = i - b * NN;
    const float* t3b = t3 + (size_t)b * NN * 3;
    int r0 = rowptr[(size_t)b * (NN + 1) + d];
    int r1 = rowptr[(size_t)b * (NN + 1) + d + 1];
    float dd = dinv[b * NN + d];
    float a0 = 0.f, a1 = 0.f, a2 = 0.f;
    const int2* cw = edgew + (size_t)b * EE;
    for (int j = r0; j < r1; j++) {
        int2 e = cw[j];
        float w = __int_as_float(e.y);
        a0 += w * t3b[e.x * 3 + 0];
        a1 += w * t3b[e.x * 3 + 1];
        a2 += w * t3b[e.x * 3 + 2];
    }
    float w = dd * dd;
    a0 += w * t3b[d * 3 + 0] + bias[0];
    a1 += w * t3b[d * 3 + 1] + bias[1];
    a2 += w * t3b[d * 3 + 2] + bias[2];
    size_t o = (size_t)i * 3;
    out[o + 0] = a0;
    out[o + 1] = a1;
    out[o + 2] = a2;
}

// ---------------- host ----------------

extern "C" void kernel_launch(void* const* d_in, const int* in_sizes, int n_in,
                              void* d_out, int out_size, void* d_ws, size_t ws_size,
                              hipStream_t stream) {
    const float* x     = (const float*)d_in[0];
    const int*   edge  = (const int*)d_in[1];
    const int*   symm  = (const int*)d_in[2];
    const float* linW  = (const float*)d_in[3];
    const float* linb  = (const float*)d_in[4];
    const float* c1W   = (const float*)d_in[5];
    const float* c1b   = (const float*)d_in[6];
    const float* blkW  = (const float*)d_in[7];
    const float* blkWs = (const float*)d_in[8];
    const float* blkb  = (const float*)d_in[9];
    const float* c3W   = (const float*)d_in[10];
    const float* c3b   = (const float*)d_in[11];

    char* ws = (char*)d_ws;
    size_t off = 0;
    auto alloc = [&](size_t bytes) -> void* {
        void* p = ws + off;
        off += (bytes + 255) & ~(size_t)255;
        return p;
    };
    ushort* xp     = (ushort*)alloc((size_t)BB * NN * 1024 * 2);  // 164 MB; us aliases after lin
    ushort* us     = xp;                                          // [B*N][256] bf16 (41 MB)
    ushort* Hb     = (ushort*)alloc((size_t)BB * NN * CH * 2);
    ushort* y      = (ushort*)alloc((size_t)BB * NN * CH * 2);
    float*  t3     = (float*) alloc((size_t)BB * NN * 3 * 4);
    ushort* linWt  = (ushort*)alloc((size_t)256 * 1024 * 2);
    ushort* c1Wt   = (ushort*)alloc((size_t)256 * 256 * 2);
    ushort* blkWc  = (ushort*)alloc((size_t)12 * 256 * 512 * 2);
    int*    cnt    = (int*)  alloc((size_t)BB * NN * 4);
    int*    fill   = (int*)  alloc((size_t)BB * NN * 4);
    float*  dinv   = (float*)alloc((size_t)BB * NN * 4);
    int*    rowptr = (int*)  alloc((size_t)BB * (NN + 1) * 4);
    int2*   edgew  = (int2*) alloc((size_t)BB * EE * 8);
    int*    symg   = (int*)  alloc((size_t)BB * NN * 4);

    float* Hf   = (float*)d_out;                  // [B,N,256] float (output 0 = final h)
    float* out2 = Hf + (size_t)BB * NN * CH;      // [B,N,3] float (output 1)

    // CSR + norm
    init_zero_kernel<<<(BB * NN + 255) / 256, 256, 0, stream>>>(cnt, fill);
    count_kernel<<<(BB * EE + 255) / 256, 256, 0, stream>>>(edge, cnt);
    dinv_kernel<<<(BB * NN + 255) / 256, 256, 0, stream>>>(cnt, dinv);
    symg_kernel<<<(BB * NN + 255) / 256, 256, 0, stream>>>(symm, symg);
    scan_kernel<<<BB, 256, 0, stream>>>(cnt, rowptr);
    fill_kernel<<<(BB * EE + 255) / 256, 256, 0, stream>>>(edge, rowptr, dinv, fill, edgew);

    // weight conversion/transpose (float -> bf16)
    wt_lin_kernel<<<(256 * 1024 + 255) / 256, 256, 0, stream>>>(linW, linWt);
    wt_sq_kernel<<<(65536 + 255) / 256, 256, 0, stream>>>(c1W, c1Wt);
    wt_cat_kernel<<<(12 * 256 * 512 + 255) / 256, 256, 0, stream>>>(blkW, blkWs, blkWc);

    int ggrid = (BB * NN) / BM;     // 625 blocks, full N=256 per block
    dim3 agrid(NN / 8, BB);         // 2500 x 4, 8 nodes/block (half-wave each)

    // lin: pad+convert all batches, one GEMM (K=1024) -> Hb (bf16)
    pad_x_kernel<<<(int)(((size_t)BB * NN * 1024 + 255) / 256), 256, 0, stream>>>(x, xp);
    gemm_bf16<<<ggrid, 512, 0, stream>>>(xp, 1024, linWt, linb, nullptr, nullptr, nullptr,
                                         Hb, BB * NN, 1024, 0);

    // conv1: u = P@x_lin; h = relu(u@c1W + c1b) -> Hb
    gather_kernel<<<agrid, 256, 0, stream>>>(Hb, dinv, rowptr, edgew, us);
    gemm_bf16<<<ggrid, 512, 0, stream>>>(us, 256, c1Wt, c1b, nullptr, nullptr, nullptr,
                                         Hb, BB * NN, 256, 1);

    // 6 GBottleneck blocks: y = relu([P@h|h[symm]]@Wc0 + b0);
    //                       h = (h + relu([P@y|y[symm]]@Wc1 + b1)) * 0.5
    // symm half read directly inside the GEMM (hsym + symg), never materialized.
    for (int i = 0; i < 6; i++) {
        const ushort* Wc0 = blkWc + (size_t)(2 * i) * 131072;
        const float*  b0  = blkb  + (size_t)(2 * i) * 256;
        const ushort* Wc1 = blkWc + (size_t)(2 * i + 1) * 131072;
        const float*  b1  = blkb  + (size_t)(2 * i + 1) * 256;

        gather_kernel<<<agrid, 256, 0, stream>>>(Hb, dinv, rowptr, edgew, us);
        gemm_bf16<<<ggrid, 512, 0, stream>>>(us, 256, Wc0, b0, nullptr, Hb, symg,
                                             y, BB * NN, 512, 1);

        gather_kernel<<<agrid, 256, 0, stream>>>(y, dinv, rowptr, edgew, us);
        gemm_bf16<<<ggrid, 512, 0, stream>>>(us, 256, Wc1, b1, Hb, y, symg,
                                             Hb, BB * NN, 512, 1);
    }

    // output 0 (h fp32) + conv3 projection, single pass over Hb
    cvt3_kernel<<<(BB * NN) / 4, 256, 0, stream>>>(Hb, c3W, Hf, t3);
    agg3_kernel<<<(BB * NN + 255) / 256, 256, 0, stream>>>(t3, c3b, dinv,
                                                           rowptr, edgew, out2);

    (void)in_sizes; (void)n_in; (void)out_size; (void)ws_size;
}

// Round 10
// 1740.612 us; speedup vs baseline: 1.5536x; 1.0063x over previous
//
#include <hip/hip_runtime.h>

#define NN 20000
#define EE 120000
#define BB 4
#define CH 256

typedef unsigned int uint;
typedef unsigned short ushort;

typedef __attribute__((ext_vector_type(8))) short bf16x8_t;
typedef __attribute__((ext_vector_type(4))) float f32x4;

__device__ __forceinline__ float bf2f(ushort h) {
    union { uint u; float f; } v; v.u = ((uint)h) << 16; return v.f;
}
__device__ __forceinline__ ushort f2bf(float f) {
    union { float f; uint u; } v; v.f = f;
    uint u = v.u;
    uint r = (u + 0x7fffu + ((u >> 16) & 1u)) >> 16;
    return (ushort)r;
}

// direct global->LDS copy, 16B per lane; LDS dest must be wave-uniform base + lane*16
__device__ __forceinline__ void gload_lds16(const ushort* g, ushort* l) {
    __builtin_amdgcn_global_load_lds((const __attribute__((address_space(1))) void*)g,
                                     (__attribute__((address_space(3))) void*)l, 16, 0, 0);
}

// ---------------- CSR build ----------------

__global__ __launch_bounds__(256) void init_zero_kernel(int* cnt, int* fill) {
    int i = blockIdx.x * 256 + threadIdx.x;
    if (i < BB * NN) { cnt[i] = 0; fill[i] = 0; }
}

__global__ __launch_bounds__(256) void count_kernel(const int* __restrict__ edge, int* cnt) {
    int i = blockIdx.x * 256 + threadIdx.x;
    if (i >= BB * EE) return;
    int b = i / EE, e = i - b * EE;
    int dst = edge[(size_t)b * 2 * EE + EE + e];
    atomicAdd(&cnt[b * NN + dst], 1);
}

__global__ __launch_bounds__(256) void dinv_kernel(const int* __restrict__ cnt, float* dinv) {
    int i = blockIdx.x * 256 + threadIdx.x;
    if (i < BB * NN) dinv[i] = rsqrtf((float)(cnt[i] + 1));
}

// flatten symm to global row index: symg[b*NN+n] = b*NN + symm[b*NN+n]
__global__ __launch_bounds__(256) void symg_kernel(const int* __restrict__ symm,
                                                   int* __restrict__ symg) {
    int i = blockIdx.x * 256 + threadIdx.x;
    if (i >= BB * NN) return;
    int b = i / NN;
    symg[i] = b * NN + symm[i];
}

__global__ __launch_bounds__(256) void scan_kernel(const int* __restrict__ cnt, int* rowptr) {
    int b = blockIdx.x;
    int t = threadIdx.x;
    int lane = t & 63, wv = t >> 6;
    __shared__ int wsum[4];
    int carry = 0;
    for (int base = 0; base < NN; base += 256) {
        int v = (base + t < NN) ? cnt[b * NN + base + t] : 0;
        int incl = v;
        #pragma unroll
        for (int off = 1; off < 64; off <<= 1) {
            int u = __shfl_up(incl, off, 64);
            if (lane >= off) incl += u;
        }
        if (lane == 63) wsum[wv] = incl;
        __syncthreads();
        int wadd = 0;
        for (int w2 = 0; w2 < wv; w2++) wadd += wsum[w2];
        int tot = wsum[0] + wsum[1] + wsum[2] + wsum[3];
        if (base + t < NN) rowptr[(size_t)b * (NN + 1) + base + t] = carry + wadd + incl - v;
        carry += tot;
        __syncthreads();
    }
    if (t == 0) rowptr[(size_t)b * (NN + 1) + NN] = carry;
}

// fill packed edge records: edgew[pos] = {src, bits(dinv[src]*dinv[dst])}
__global__ __launch_bounds__(256) void fill_kernel(const int* __restrict__ edge,
                                                   const int* __restrict__ rowptr,
                                                   const float* __restrict__ dinv,
                                                   int* fill, int2* edgew) {
    int i = blockIdx.x * 256 + threadIdx.x;
    if (i >= BB * EE) return;
    int b = i / EE, e = i - b * EE;
    int src = edge[(size_t)b * 2 * EE + e];
    int dst = edge[(size_t)b * 2 * EE + EE + e];
    int pos = rowptr[(size_t)b * (NN + 1) + dst] + atomicAdd(&fill[b * NN + dst], 1);
    float w = dinv[b * NN + src] * dinv[b * NN + dst];
    edgew[(size_t)b * EE + pos] = make_int2(src, __float_as_int(w));
}

// ---------------- weight prep (float32 -> bf16) ----------------

__global__ __launch_bounds__(256) void wt_sq_kernel(const float* __restrict__ src,
                                                    ushort* __restrict__ dst) {
    int i = blockIdx.x * 256 + threadIdx.x;
    if (i >= 65536) return;
    int n = i >> 8, k = i & 255;
    dst[i] = f2bf(src[(k << 8) + n]);
}

// concat [W;Ws] per layer: dst bf16 [12][256 n][512 k]
__global__ __launch_bounds__(256) void wt_cat_kernel(const float* __restrict__ W,
                                                     const float* __restrict__ Ws,
                                                     ushort* __restrict__ dst) {
    int i = blockIdx.x * 256 + threadIdx.x;
    if (i >= 12 * 256 * 512) return;
    int mat = i >> 17;
    int rem = i & 131071;
    int n = rem >> 9, k = rem & 511;
    float v = (k < 256) ? W[(mat << 16) + (k << 8) + n]
                        : Ws[(mat << 16) + ((k - 256) << 8) + n];
    dst[i] = f2bf(v);
}

// src float [963][256] -> dst bf16 [256][1024] (zero-padded K)
__global__ __launch_bounds__(256) void wt_lin_kernel(const float* __restrict__ src,
                                                     ushort* __restrict__ dst) {
    int i = blockIdx.x * 256 + threadIdx.x;
    if (i >= 256 * 1024) return;
    int n = i >> 10, k = i & 1023;
    dst[i] = (k < 963) ? f2bf(src[k * 256 + n]) : (ushort)0;
}

// x float [80000][963] -> xp bf16 [80000][1024] zero-padded
__global__ __launch_bounds__(256) void pad_x_kernel(const float* __restrict__ x,
                                                    ushort* __restrict__ xp) {
    size_t i = (size_t)blockIdx.x * 256 + threadIdx.x;
    if (i >= (size_t)BB * NN * 1024) return;
    size_t row = i >> 10;
    int k = (int)(i & 1023);
    xp[i] = (k < 963) ? f2bf(x[row * 963 + k]) : (ushort)0;
}

// ---------------- gather: us[d] = P@h (256ch, bf16) ----------------
// HALF-WAVE per dst node: 32 lanes x uint4 (16B) = 512B = one full 256ch bf16 row.
// Each wave serves 2 nodes; chunk-of-4 edges keeps 4 row-loads (64B/lane) in flight.
// packed edge records (src, weight) -> one dependent load per edge.

__device__ __forceinline__ void acc8(float* a, float w, uint4 v) {
    const uint* vp = (const uint*)&v;
    #pragma unroll
    for (int q = 0; q < 4; q++) {
        a[2 * q]     += w * bf2f((ushort)(vp[q] & 0xffff));
        a[2 * q + 1] += w * bf2f((ushort)(vp[q] >> 16));
    }
}

__global__ __launch_bounds__(256) void gather_kernel(const ushort* __restrict__ h,
                                                     const float* __restrict__ dinv,
                                                     const int* __restrict__ rowptr,
                                                     const int2* __restrict__ edgew,
                                                     ushort* __restrict__ us) {
    int t = threadIdx.x;
    int hw = t >> 5, lane32 = t & 31;
    int d = blockIdx.x * 8 + hw;
    int b = blockIdx.y;
    const ushort* hb = h + (size_t)b * NN * CH;
    int co = lane32 * 8;
    int r0 = rowptr[(size_t)b * (NN + 1) + d];
    int r1 = rowptr[(size_t)b * (NN + 1) + d + 1];
    float dd = dinv[b * NN + d];
    const int2* cw = edgew + (size_t)b * EE;
    float a[8];
    {   // self loop
        float w = dd * dd;
        uint4 v = *(const uint4*)(hb + (size_t)d * CH + co);
        const uint* vp = (const uint*)&v;
        #pragma unroll
        for (int q = 0; q < 4; q++) {
            a[2 * q]     = w * bf2f((ushort)(vp[q] & 0xffff));
            a[2 * q + 1] = w * bf2f((ushort)(vp[q] >> 16));
        }
    }
    int j = r0;
    for (; j + 4 <= r1; j += 4) {
        int2 e0 = cw[j], e1 = cw[j + 1], e2 = cw[j + 2], e3 = cw[j + 3];
        uint4 v0 = *(const uint4*)(hb + (size_t)e0.x * CH + co);
        uint4 v1 = *(const uint4*)(hb + (size_t)e1.x * CH + co);
        uint4 v2 = *(const uint4*)(hb + (size_t)e2.x * CH + co);
        uint4 v3 = *(const uint4*)(hb + (size_t)e3.x * CH + co);
        acc8(a, __int_as_float(e0.y), v0);
        acc8(a, __int_as_float(e1.y), v1);
        acc8(a, __int_as_float(e2.y), v2);
        acc8(a, __int_as_float(e3.y), v3);
    }
    for (; j < r1; j++) {
        int2 e = cw[j];
        uint4 v = *(const uint4*)(hb + (size_t)e.x * CH + co);
        acc8(a, __int_as_float(e.y), v);
    }
    uint o[4];
    #pragma unroll
    for (int q = 0; q < 4; q++)
        o[q] = (uint)f2bf(a[2 * q]) | ((uint)f2bf(a[2 * q + 1]) << 16);
    size_t orow = ((size_t)b * NN + d) * CH;
    *(uint4*)(us + orow + co) = *(const uint4*)o;
}

// ---------------- MFMA GEMM: C[M][256] = A[M][K] @ Wt^T + bias (relu) (resid avg) ----------
// 512 threads, BM=128, BN=256 (full width), BK=64. XOR-swizzled LDS (LDK=64, no pad).
// Staging via global_load_lds (16B/lane, direct to LDS): no staging VGPRs, no spill.
// LDS DIET: 48 KB total (staging 48 KB; epilogue reuses 32 KB of it via TWO 32-row
// passes of 4 KB/wave) -> 3 blocks/CU (was 64 KB -> 2 blocks/CU). +50% resident waves
// to cover the barrier-drain latency of the single-buffer staging loop.
// Swizzle achieved by PRE-SWIZZLING the per-lane GLOBAL source chunk (ch ^ (row&7));
// LDS dest stays linear (base + lane*16) as HW requires. Reader layout unchanged.
// A columns: [0,256) from A (lda stride); [256,512) (when hsym!=null) read directly from
//            hsym[symg[row]] — the symm copy is never materialized.

#define BM 128

__global__ __launch_bounds__(512, 4) void gemm_bf16(const ushort* __restrict__ A, int lda,
                                                    const ushort* __restrict__ Wt,
                                                    const float* __restrict__ bias,
                                                    const ushort* __restrict__ resid,
                                                    const ushort* __restrict__ hsym,
                                                    const int* __restrict__ symg,
                                                    ushort* __restrict__ outb,
                                                    int M, int K, int relu) {
    __shared__ __align__(16) ushort smem[24576];  // 48 KB: A 16 KB + B 32 KB; epilogue reuses 32 KB
    ushort* As = smem;            // [128][64] swizzled
    ushort* Bs = smem + 128 * 64; // [256][64] swizzled
    int t = threadIdx.x;
    int lane = t & 63, wv = t >> 6;
    int m0 = blockIdx.x * BM;
    int lm = lane & 15, quad = lane >> 4;
    int wm = (wv >> 2) * 64;   // 2 m-halves
    int wn = (wv & 3) * 64;    // 4 n-quarters

    // staging geometry: thread t covers row = p*64 + (t>>3), global chunk (t&7)^(srow&7)
    int srow = t >> 3, sch = t & 7;
    int gch = sch ^ (srow & 7);          // p*64 doesn't change row&7

    const ushort* aP[2];   // A source (swizzle baked in)
    const ushort* sP[2];   // hsym source (pre-shifted by -256 so +kt works)
    ushort* aL[2];         // linear LDS dest
    #pragma unroll
    for (int p = 0; p < 2; p++) {
        int row = p * 64 + srow;
        aP[p] = A + (size_t)(m0 + row) * lda + gch * 8;
        aL[p] = As + (p * 512 + t) * 8;
        sP[p] = aP[p];
    }
    if (hsym) {
        #pragma unroll
        for (int p = 0; p < 2; p++) {
            int sy = symg[m0 + p * 64 + srow];
            sP[p] = hsym + (size_t)sy * CH - 256 + gch * 8;
        }
    }
    const ushort* bP[4];
    ushort* bL[4];
    #pragma unroll
    for (int p = 0; p < 4; p++) {
        int row = p * 64 + srow;
        bP[p] = Wt + (size_t)row * K + gch * 8;
        bL[p] = Bs + (p * 512 + t) * 8;
    }

    f32x4 acc[4][4];
    #pragma unroll
    for (int i = 0; i < 4; i++)
        #pragma unroll
        for (int j = 0; j < 4; j++) acc[i][j] = (f32x4){0.f, 0.f, 0.f, 0.f};

    for (int kt = 0; kt < K; kt += 64) {
        __syncthreads();  // all waves done reading LDS from previous tile
        bool useSym = hsym && (kt >= 256);
        #pragma unroll
        for (int p = 0; p < 2; p++)
            gload_lds16((useSym ? sP[p] : aP[p]) + kt, aL[p]);
        #pragma unroll
        for (int p = 0; p < 4; p++)
            gload_lds16(bP[p] + kt, bL[p]);
        __syncthreads();  // vmcnt(0) drain at barrier: LDS tile ready
        #pragma unroll
        for (int ks = 0; ks < 2; ks++) {
            bf16x8_t af[4];
            #pragma unroll
            for (int i = 0; i < 4; i++) {
                int row = wm + i * 16 + lm;
                int chunk = (ks * 4 + quad) ^ (row & 7);
                af[i] = *(const bf16x8_t*)(As + row * 64 + chunk * 8);
            }
            #pragma unroll
            for (int j = 0; j < 4; j++) {
                int row = wn + j * 16 + lm;
                int chunk = (ks * 4 + quad) ^ (row & 7);
                bf16x8_t bfr = *(const bf16x8_t*)(Bs + row * 64 + chunk * 8);
                #pragma unroll
                for (int i = 0; i < 4; i++)
                    acc[i][j] = __builtin_amdgcn_mfma_f32_16x16x32_bf16(af[i], bfr, acc[i][j], 0, 0, 0);
            }
        }
    }

    // ---- epilogue: two 32-row passes, 4 KB/wave LDS (fits inside the 48 KB) ----
    float bj[4];
    #pragma unroll
    for (int j = 0; j < 4; j++) bj[j] = bias[wn + j * 16 + lm];
    int rl = lane >> 3, c8 = lane & 7;
    ushort* eb = smem + wv * 2048;  // 32 rows x 64 cols per pass, chunk-swizzled by row&7
    #pragma unroll
    for (int pass = 0; pass < 2; pass++) {
        __syncthreads();  // pass 0: staging reads done; pass 1: previous pass reads done
        #pragma unroll
        for (int ih = 0; ih < 2; ih++) {
            int i = pass * 2 + ih;
            #pragma unroll
            for (int r = 0; r < 4; r++) {
                int lr = ih * 16 + quad * 4 + r;  // 0..31 (lr&7 == row&7: 32-aligned split)
                int sw = lr & 7;
                #pragma unroll
                for (int j = 0; j < 4; j++) {
                    int col = j * 16 + lm;
                    int scol = ((((col >> 3) ^ sw)) << 3) | (col & 7);
                    float v = acc[i][j][r] + bj[j];
                    if (relu) v = fmaxf(v, 0.f);
                    eb[lr * 64 + scol] = f2bf(v);
                }
            }
        }
        // wave-local readback + coalesced store (8 rows x 128B full lines per instr)
        #pragma unroll
        for (int s = 0; s < 4; s++) {
            int lr = s * 8 + rl;  // 0..31
            int row = pass * 32 + lr;
            int chunk = c8 ^ (lr & 7);
            uint4 v = *(const uint4*)(eb + lr * 64 + chunk * 8);
            size_t ga = (size_t)(m0 + wm + row) * CH + wn + c8 * 8;
            if (resid) {
                uint4 h = *(const uint4*)(resid + ga);
                uint res[4];
                const uint* vp = (const uint*)&v;
                const uint* hp = (const uint*)&h;
                #pragma unroll
                for (int w = 0; w < 4; w++) {
                    float y0 = bf2f((ushort)(vp[w] & 0xffff));
                    float y1 = bf2f((ushort)(vp[w] >> 16));
                    float h0 = bf2f((ushort)(hp[w] & 0xffff));
                    float h1 = bf2f((ushort)(hp[w] >> 16));
                    res[w] = (uint)f2bf((h0 + y0) * 0.5f) | ((uint)f2bf((h1 + y1) * 0.5f) << 16);
                }
                v = *(uint4*)res;
            }
            *(uint4*)(outb + ga) = v;
        }
    }
}

// ---------------- fused: h (bf16) -> output 0 (fp32)  AND  h @ W3 -> t3 ----------------

__global__ __launch_bounds__(256) void cvt3_kernel(const ushort* __restrict__ Hb,
                                                   const float* __restrict__ W3,
                                                   float* __restrict__ Hf,
                                                   float* __restrict__ t3) {
    int wv = threadIdx.x >> 6, lane = threadIdx.x & 63;
    int nd = blockIdx.x * 4 + wv;  // [0, BB*NN)
    uint2 hv = *(const uint2*)(Hb + (size_t)nd * CH + lane * 4);
    float hp[4];
    hp[0] = bf2f((ushort)(hv.x & 0xffff));
    hp[1] = bf2f((ushort)(hv.x >> 16));
    hp[2] = bf2f((ushort)(hv.y & 0xffff));
    hp[3] = bf2f((ushort)(hv.y >> 16));
    float4 o;
    o.x = hp[0]; o.y = hp[1]; o.z = hp[2]; o.w = hp[3];
    *(float4*)(Hf + (size_t)nd * CH + lane * 4) = o;
    int k0 = lane * 4;
    float s0 = 0.f, s1 = 0.f, s2 = 0.f;
    #pragma unroll
    for (int j = 0; j < 4; j++) {
        float h = hp[j];
        s0 += h * W3[(k0 + j) * 3 + 0];
        s1 += h * W3[(k0 + j) * 3 + 1];
        s2 += h * W3[(k0 + j) * 3 + 2];
    }
    #pragma unroll
    for (int off = 32; off; off >>= 1) {
        s0 += __shfl_down(s0, off, 64);
        s1 += __shfl_down(s1, off, 64);
        s2 += __shfl_down(s2, off, 64);
    }
    if (lane == 0) {
        t3[(size_t)nd * 3 + 0] = s0;
        t3[(size_t)nd * 3 + 1] = s1;
        t3[(size_t)nd * 3 + 2] = s2;
    }
}

__global__ __launch_bounds__(256) void agg3_kernel(const float* __restrict__ t3,
                                                   const float* __restrict__ bias,
                                                   const float* __restrict__ dinv,
                                                   const int* __restrict__ rowptr,
                                                   const int2* __restrict__ edgew,
                                                   float* __restrict__ out) {
    int i = blockIdx.x * 256 + threadIdx.x;
    if (i >= BB * NN) return;
    int b = i / NN, d = i - b * NN;
    const float* t3b = t3 + (size_t)b * NN * 3;
    int r0 = rowptr[(size_t)b * (NN + 1) + d];
    int r1 = rowptr[(size_t)b * (NN + 1) + d + 1];
    float dd = dinv[b * NN + d];
    float a0 = 0.f, a1 = 0.f, a2 = 0.f;
    const int2* cw = edgew + (size_t)b * EE;
    for (int j = r0; j < r1; j++) {
        int2 e = cw[j];
        float w = __int_as_float(e.y);
        a0 += w * t3b[e.x * 3 + 0];
        a1 += w * t3b[e.x * 3 + 1];
        a2 += w * t3b[e.x * 3 + 2];
    }
    float w = dd * dd;
    a0 += w * t3b[d * 3 + 0] + bias[0];
    a1 += w * t3b[d * 3 + 1] + bias[1];
    a2 += w * t3b[d * 3 + 2] + bias[2];
    size_t o = (size_t)i * 3;
    out[o + 0] = a0;
    out[o + 1] = a1;
    out[o + 2] = a2;
}

// ---------------- host ----------------

extern "C" void kernel_launch(void* const* d_in, const int* in_sizes, int n_in,
                              void* d_out, int out_size, void* d_ws, size_t ws_size,
                              hipStream_t stream) {
    const float* x     = (const float*)d_in[0];
    const int*   edge  = (const int*)d_in[1];
    const int*   symm  = (const int*)d_in[2];
    const float* linW  = (const float*)d_in[3];
    const float* linb  = (const float*)d_in[4];
    const float* c1W   = (const float*)d_in[5];
    const float* c1b   = (const float*)d_in[6];
    const float* blkW  = (const float*)d_in[7];
    const float* blkWs = (const float*)d_in[8];
    const float* blkb  = (const float*)d_in[9];
    const float* c3W   = (const float*)d_in[10];
    const float* c3b   = (const float*)d_in[11];

    char* ws = (char*)d_ws;
    size_t off = 0;
    auto alloc = [&](size_t bytes) -> void* {
        void* p = ws + off;
        off += (bytes + 255) & ~(size_t)255;
        return p;
    };
    ushort* xp     = (ushort*)alloc((size_t)BB * NN * 1024 * 2);  // 164 MB; us aliases after lin
    ushort* us     = xp;                                          // [B*N][256] bf16 (41 MB)
    ushort* Hb     = (ushort*)alloc((size_t)BB * NN * CH * 2);
    ushort* y      = (ushort*)alloc((size_t)BB * NN * CH * 2);
    float*  t3     = (float*) alloc((size_t)BB * NN * 3 * 4);
    ushort* linWt  = (ushort*)alloc((size_t)256 * 1024 * 2);
    ushort* c1Wt   = (ushort*)alloc((size_t)256 * 256 * 2);
    ushort* blkWc  = (ushort*)alloc((size_t)12 * 256 * 512 * 2);
    int*    cnt    = (int*)  alloc((size_t)BB * NN * 4);
    int*    fill   = (int*)  alloc((size_t)BB * NN * 4);
    float*  dinv   = (float*)alloc((size_t)BB * NN * 4);
    int*    rowptr = (int*)  alloc((size_t)BB * (NN + 1) * 4);
    int2*   edgew  = (int2*) alloc((size_t)BB * EE * 8);
    int*    symg   = (int*)  alloc((size_t)BB * NN * 4);

    float* Hf   = (float*)d_out;                  // [B,N,256] float (output 0 = final h)
    float* out2 = Hf + (size_t)BB * NN * CH;      // [B,N,3] float (output 1)

    // CSR + norm
    init_zero_kernel<<<(BB * NN + 255) / 256, 256, 0, stream>>>(cnt, fill);
    count_kernel<<<(BB * EE + 255) / 256, 256, 0, stream>>>(edge, cnt);
    dinv_kernel<<<(BB * NN + 255) / 256, 256, 0, stream>>>(cnt, dinv);
    symg_kernel<<<(BB * NN + 255) / 256, 256, 0, stream>>>(symm, symg);
    scan_kernel<<<BB, 256, 0, stream>>>(cnt, rowptr);
    fill_kernel<<<(BB * EE + 255) / 256, 256, 0, stream>>>(edge, rowptr, dinv, fill, edgew);

    // weight conversion/transpose (float -> bf16)
    wt_lin_kernel<<<(256 * 1024 + 255) / 256, 256, 0, stream>>>(linW, linWt);
    wt_sq_kernel<<<(65536 + 255) / 256, 256, 0, stream>>>(c1W, c1Wt);
    wt_cat_kernel<<<(12 * 256 * 512 + 255) / 256, 256, 0, stream>>>(blkW, blkWs, blkWc);

    int ggrid = (BB * NN) / BM;     // 625 blocks, full N=256 per block
    dim3 agrid(NN / 8, BB);         // 2500 x 4, 8 nodes/block (half-wave each)

    // lin: pad+convert all batches, one GEMM (K=1024) -> Hb (bf16)
    pad_x_kernel<<<(int)(((size_t)BB * NN * 1024 + 255) / 256), 256, 0, stream>>>(x, xp);
    gemm_bf16<<<ggrid, 512, 0, stream>>>(xp, 1024, linWt, linb, nullptr, nullptr, nullptr,
                                         Hb, BB * NN, 1024, 0);

    // conv1: u = P@x_lin; h = relu(u@c1W + c1b) -> Hb
    gather_kernel<<<agrid, 256, 0, stream>>>(Hb, dinv, rowptr, edgew, us);
    gemm_bf16<<<ggrid, 512, 0, stream>>>(us, 256, c1Wt, c1b, nullptr, nullptr, nullptr,
                                         Hb, BB * NN, 256, 1);

    // 6 GBottleneck blocks: y = relu([P@h|h[symm]]@Wc0 + b0);
    //                       h = (h + relu([P@y|y[symm]]@Wc1 + b1)) * 0.5
    // symm half read directly inside the GEMM (hsym + symg), never materialized.
    for (int i = 0; i < 6; i++) {
        const ushort* Wc0 = blkWc + (size_t)(2 * i) * 131072;
        const float*  b0  = blkb  + (size_t)(2 * i) * 256;
        const ushort* Wc1 = blkWc + (size_t)(2 * i + 1) * 131072;
        const float*  b1  = blkb  + (size_t)(2 * i + 1) * 256;

        gather_kernel<<<agrid, 256, 0, stream>>>(Hb, dinv, rowptr, edgew, us);
        gemm_bf16<<<ggrid, 512, 0, stream>>>(us, 256, Wc0, b0, nullptr, Hb, symg,
                                             y, BB * NN, 512, 1);

        gather_kernel<<<agrid, 256, 0, stream>>>(y, dinv, rowptr, edgew, us);
        gemm_bf16<<<ggrid, 512, 0, stream>>>(us, 256, Wc1, b1, Hb, y, symg,
                                             Hb, BB * NN, 512, 1);
    }

    // output 0 (h fp32) + conv3 projection, single pass over Hb
    cvt3_kernel<<<(BB * NN) / 4, 256, 0, stream>>>(Hb, c3W, Hf, t3);
    agg3_kernel<<<(BB * NN + 255) / 256, 256, 0, stream>>>(t3, c3b, dinv,
                                                           rowptr, edgew, out2);

    (void)in_sizes; (void)n_in; (void)out_size; (void)ws_size;
}

// Round 11
// 1661.362 us; speedup vs baseline: 1.6277x; 1.0477x over previous
//
#include <hip/hip_runtime.h>

#define NN 20000
#define EE 120000
#define BB 4
#define CH 256

typedef unsigned int uint;
typedef unsigned short ushort;

typedef __attribute__((ext_vector_type(8))) short bf16x8_t;
typedef __attribute__((ext_vector_type(4))) float f32x4;

__device__ __forceinline__ float bf2f(ushort h) {
    union { uint u; float f; } v; v.u = ((uint)h) << 16; return v.f;
}
__device__ __forceinline__ ushort f2bf(float f) {
    union { float f; uint u; } v; v.f = f;
    uint u = v.u;
    uint r = (u + 0x7fffu + ((u >> 16) & 1u)) >> 16;
    return (ushort)r;
}

// direct global->LDS copy, 16B per lane; LDS dest must be wave-uniform base + lane*16
__device__ __forceinline__ void gload_lds16(const ushort* g, ushort* l) {
    __builtin_amdgcn_global_load_lds((const __attribute__((address_space(1))) void*)g,
                                     (__attribute__((address_space(3))) void*)l, 16, 0, 0);
}

// ---------------- CSR build ----------------

__global__ __launch_bounds__(256) void init_zero_kernel(int* cnt, int* fill) {
    int i = blockIdx.x * 256 + threadIdx.x;
    if (i < BB * NN) { cnt[i] = 0; fill[i] = 0; }
}

__global__ __launch_bounds__(256) void count_kernel(const int* __restrict__ edge, int* cnt) {
    int i = blockIdx.x * 256 + threadIdx.x;
    if (i >= BB * EE) return;
    int b = i / EE, e = i - b * EE;
    int dst = edge[(size_t)b * 2 * EE + EE + e];
    atomicAdd(&cnt[b * NN + dst], 1);
}

__global__ __launch_bounds__(256) void dinv_kernel(const int* __restrict__ cnt, float* dinv) {
    int i = blockIdx.x * 256 + threadIdx.x;
    if (i < BB * NN) dinv[i] = rsqrtf((float)(cnt[i] + 1));
}

// flatten symm to global row index: symg[b*NN+n] = b*NN + symm[b*NN+n]
__global__ __launch_bounds__(256) void symg_kernel(const int* __restrict__ symm,
                                                   int* __restrict__ symg) {
    int i = blockIdx.x * 256 + threadIdx.x;
    if (i >= BB * NN) return;
    int b = i / NN;
    symg[i] = b * NN + symm[i];
}

__global__ __launch_bounds__(256) void scan_kernel(const int* __restrict__ cnt, int* rowptr) {
    int b = blockIdx.x;
    int t = threadIdx.x;
    int lane = t & 63, wv = t >> 6;
    __shared__ int wsum[4];
    int carry = 0;
    for (int base = 0; base < NN; base += 256) {
        int v = (base + t < NN) ? cnt[b * NN + base + t] : 0;
        int incl = v;
        #pragma unroll
        for (int off = 1; off < 64; off <<= 1) {
            int u = __shfl_up(incl, off, 64);
            if (lane >= off) incl += u;
        }
        if (lane == 63) wsum[wv] = incl;
        __syncthreads();
        int wadd = 0;
        for (int w2 = 0; w2 < wv; w2++) wadd += wsum[w2];
        int tot = wsum[0] + wsum[1] + wsum[2] + wsum[3];
        if (base + t < NN) rowptr[(size_t)b * (NN + 1) + base + t] = carry + wadd + incl - v;
        carry += tot;
        __syncthreads();
    }
    if (t == 0) rowptr[(size_t)b * (NN + 1) + NN] = carry;
}

// fill packed edge records: edgew[pos] = {src, bits(dinv[src]*dinv[dst])}
__global__ __launch_bounds__(256) void fill_kernel(const int* __restrict__ edge,
                                                   const int* __restrict__ rowptr,
                                                   const float* __restrict__ dinv,
                                                   int* fill, int2* edgew) {
    int i = blockIdx.x * 256 + threadIdx.x;
    if (i >= BB * EE) return;
    int b = i / EE, e = i - b * EE;
    int src = edge[(size_t)b * 2 * EE + e];
    int dst = edge[(size_t)b * 2 * EE + EE + e];
    int pos = rowptr[(size_t)b * (NN + 1) + dst] + atomicAdd(&fill[b * NN + dst], 1);
    float w = dinv[b * NN + src] * dinv[b * NN + dst];
    edgew[(size_t)b * EE + pos] = make_int2(src, __float_as_int(w));
}

// ---------------- weight prep (float32 -> bf16) ----------------

__global__ __launch_bounds__(256) void wt_sq_kernel(const float* __restrict__ src,
                                                    ushort* __restrict__ dst) {
    int i = blockIdx.x * 256 + threadIdx.x;
    if (i >= 65536) return;
    int n = i >> 8, k = i & 255;
    dst[i] = f2bf(src[(k << 8) + n]);
}

// concat [W;Ws] per layer: dst bf16 [12][256 n][512 k]
__global__ __launch_bounds__(256) void wt_cat_kernel(const float* __restrict__ W,
                                                     const float* __restrict__ Ws,
                                                     ushort* __restrict__ dst) {
    int i = blockIdx.x * 256 + threadIdx.x;
    if (i >= 12 * 256 * 512) return;
    int mat = i >> 17;
    int rem = i & 131071;
    int n = rem >> 9, k = rem & 511;
    float v = (k < 256) ? W[(mat << 16) + (k << 8) + n]
                        : Ws[(mat << 16) + ((k - 256) << 8) + n];
    dst[i] = f2bf(v);
}

// src float [963][256] -> dst bf16 [256][1024] (zero-padded K)
__global__ __launch_bounds__(256) void wt_lin_kernel(const float* __restrict__ src,
                                                     ushort* __restrict__ dst) {
    int i = blockIdx.x * 256 + threadIdx.x;
    if (i >= 256 * 1024) return;
    int n = i >> 10, k = i & 1023;
    dst[i] = (k < 963) ? f2bf(src[k * 256 + n]) : (ushort)0;
}

// ---------------- gather: us[d] = P@h (256ch, bf16) ----------------
// HALF-WAVE per dst node: 32 lanes x uint4 (16B) = 512B = one full 256ch bf16 row.
// Each wave serves 2 nodes; chunk-of-4 edges keeps 4 row-loads (64B/lane) in flight.
// packed edge records (src, weight) -> one dependent load per edge.

__device__ __forceinline__ void acc8(float* a, float w, uint4 v) {
    const uint* vp = (const uint*)&v;
    #pragma unroll
    for (int q = 0; q < 4; q++) {
        a[2 * q]     += w * bf2f((ushort)(vp[q] & 0xffff));
        a[2 * q + 1] += w * bf2f((ushort)(vp[q] >> 16));
    }
}

__global__ __launch_bounds__(256) void gather_kernel(const ushort* __restrict__ h,
                                                     const float* __restrict__ dinv,
                                                     const int* __restrict__ rowptr,
                                                     const int2* __restrict__ edgew,
                                                     ushort* __restrict__ us) {
    int t = threadIdx.x;
    int hw = t >> 5, lane32 = t & 31;
    int d = blockIdx.x * 8 + hw;
    int b = blockIdx.y;
    const ushort* hb = h + (size_t)b * NN * CH;
    int co = lane32 * 8;
    int r0 = rowptr[(size_t)b * (NN + 1) + d];
    int r1 = rowptr[(size_t)b * (NN + 1) + d + 1];
    float dd = dinv[b * NN + d];
    const int2* cw = edgew + (size_t)b * EE;
    float a[8];
    {   // self loop
        float w = dd * dd;
        uint4 v = *(const uint4*)(hb + (size_t)d * CH + co);
        const uint* vp = (const uint*)&v;
        #pragma unroll
        for (int q = 0; q < 4; q++) {
            a[2 * q]     = w * bf2f((ushort)(vp[q] & 0xffff));
            a[2 * q + 1] = w * bf2f((ushort)(vp[q] >> 16));
        }
    }
    int j = r0;
    for (; j + 4 <= r1; j += 4) {
        int2 e0 = cw[j], e1 = cw[j + 1], e2 = cw[j + 2], e3 = cw[j + 3];
        uint4 v0 = *(const uint4*)(hb + (size_t)e0.x * CH + co);
        uint4 v1 = *(const uint4*)(hb + (size_t)e1.x * CH + co);
        uint4 v2 = *(const uint4*)(hb + (size_t)e2.x * CH + co);
        uint4 v3 = *(const uint4*)(hb + (size_t)e3.x * CH + co);
        acc8(a, __int_as_float(e0.y), v0);
        acc8(a, __int_as_float(e1.y), v1);
        acc8(a, __int_as_float(e2.y), v2);
        acc8(a, __int_as_float(e3.y), v3);
    }
    for (; j < r1; j++) {
        int2 e = cw[j];
        uint4 v = *(const uint4*)(hb + (size_t)e.x * CH + co);
        acc8(a, __int_as_float(e.y), v);
    }
    uint o[4];
    #pragma unroll
    for (int q = 0; q < 4; q++)
        o[q] = (uint)f2bf(a[2 * q]) | ((uint)f2bf(a[2 * q + 1]) << 16);
    size_t orow = ((size_t)b * NN + d) * CH;
    *(uint4*)(us + orow + co) = *(const uint4*)o;
}

// ---------------- MFMA GEMM: C[M][256] = A[M][K] @ Wt^T + bias (relu) (resid avg) ----------
// 512 threads, BM=128, BN=256 (full width), BK=64. XOR-swizzled LDS (LDK=64, no pad).
// Staging via global_load_lds (16B/lane, direct to LDS): no staging VGPRs, no spill.
// 48 KB LDS total; epilogue reuses 32 KB via two 32-row passes (3 blocks/CU).
// Swizzle achieved by PRE-SWIZZLING the per-lane GLOBAL source chunk (ch ^ (row&7));
// LDS dest stays linear (base + lane*16) as HW requires. Reader layout unchanged.
// A columns: [0,256) from A (lda stride); [256,512) (when hsym!=null) read directly from
//            hsym[symg[row]] — the symm copy is never materialized.

#define BM 128

__global__ __launch_bounds__(512, 4) void gemm_bf16(const ushort* __restrict__ A, int lda,
                                                    const ushort* __restrict__ Wt,
                                                    const float* __restrict__ bias,
                                                    const ushort* __restrict__ resid,
                                                    const ushort* __restrict__ hsym,
                                                    const int* __restrict__ symg,
                                                    ushort* __restrict__ outb,
                                                    int M, int K, int relu) {
    __shared__ __align__(16) ushort smem[24576];  // 48 KB: A 16 KB + B 32 KB; epilogue reuses 32 KB
    ushort* As = smem;            // [128][64] swizzled
    ushort* Bs = smem + 128 * 64; // [256][64] swizzled
    int t = threadIdx.x;
    int lane = t & 63, wv = t >> 6;
    int m0 = blockIdx.x * BM;
    int lm = lane & 15, quad = lane >> 4;
    int wm = (wv >> 2) * 64;   // 2 m-halves
    int wn = (wv & 3) * 64;    // 4 n-quarters

    // staging geometry: thread t covers row = p*64 + (t>>3), global chunk (t&7)^(srow&7)
    int srow = t >> 3, sch = t & 7;
    int gch = sch ^ (srow & 7);          // p*64 doesn't change row&7

    const ushort* aP[2];   // A source (swizzle baked in)
    const ushort* sP[2];   // hsym source (pre-shifted by -256 so +kt works)
    ushort* aL[2];         // linear LDS dest
    #pragma unroll
    for (int p = 0; p < 2; p++) {
        int row = p * 64 + srow;
        aP[p] = A + (size_t)(m0 + row) * lda + gch * 8;
        aL[p] = As + (p * 512 + t) * 8;
        sP[p] = aP[p];
    }
    if (hsym) {
        #pragma unroll
        for (int p = 0; p < 2; p++) {
            int sy = symg[m0 + p * 64 + srow];
            sP[p] = hsym + (size_t)sy * CH - 256 + gch * 8;
        }
    }
    const ushort* bP[4];
    ushort* bL[4];
    #pragma unroll
    for (int p = 0; p < 4; p++) {
        int row = p * 64 + srow;
        bP[p] = Wt + (size_t)row * K + gch * 8;
        bL[p] = Bs + (p * 512 + t) * 8;
    }

    f32x4 acc[4][4];
    #pragma unroll
    for (int i = 0; i < 4; i++)
        #pragma unroll
        for (int j = 0; j < 4; j++) acc[i][j] = (f32x4){0.f, 0.f, 0.f, 0.f};

    for (int kt = 0; kt < K; kt += 64) {
        __syncthreads();  // all waves done reading LDS from previous tile
        bool useSym = hsym && (kt >= 256);
        #pragma unroll
        for (int p = 0; p < 2; p++)
            gload_lds16((useSym ? sP[p] : aP[p]) + kt, aL[p]);
        #pragma unroll
        for (int p = 0; p < 4; p++)
            gload_lds16(bP[p] + kt, bL[p]);
        __syncthreads();  // vmcnt(0) drain at barrier: LDS tile ready
        #pragma unroll
        for (int ks = 0; ks < 2; ks++) {
            bf16x8_t af[4];
            #pragma unroll
            for (int i = 0; i < 4; i++) {
                int row = wm + i * 16 + lm;
                int chunk = (ks * 4 + quad) ^ (row & 7);
                af[i] = *(const bf16x8_t*)(As + row * 64 + chunk * 8);
            }
            #pragma unroll
            for (int j = 0; j < 4; j++) {
                int row = wn + j * 16 + lm;
                int chunk = (ks * 4 + quad) ^ (row & 7);
                bf16x8_t bfr = *(const bf16x8_t*)(Bs + row * 64 + chunk * 8);
                #pragma unroll
                for (int i = 0; i < 4; i++)
                    acc[i][j] = __builtin_amdgcn_mfma_f32_16x16x32_bf16(af[i], bfr, acc[i][j], 0, 0, 0);
            }
        }
    }

    // ---- epilogue: two 32-row passes, 4 KB/wave LDS (fits inside the 48 KB) ----
    float bj[4];
    #pragma unroll
    for (int j = 0; j < 4; j++) bj[j] = bias[wn + j * 16 + lm];
    int rl = lane >> 3, c8 = lane & 7;
    ushort* eb = smem + wv * 2048;  // 32 rows x 64 cols per pass, chunk-swizzled by row&7
    #pragma unroll
    for (int pass = 0; pass < 2; pass++) {
        __syncthreads();  // pass 0: staging reads done; pass 1: previous pass reads done
        #pragma unroll
        for (int ih = 0; ih < 2; ih++) {
            int i = pass * 2 + ih;
            #pragma unroll
            for (int r = 0; r < 4; r++) {
                int lr = ih * 16 + quad * 4 + r;  // 0..31 (lr&7 == row&7: 32-aligned split)
                int sw = lr & 7;
                #pragma unroll
                for (int j = 0; j < 4; j++) {
                    int col = j * 16 + lm;
                    int scol = ((((col >> 3) ^ sw)) << 3) | (col & 7);
                    float v = acc[i][j][r] + bj[j];
                    if (relu) v = fmaxf(v, 0.f);
                    eb[lr * 64 + scol] = f2bf(v);
                }
            }
        }
        // wave-local readback + coalesced store (8 rows x 128B full lines per instr)
        #pragma unroll
        for (int s = 0; s < 4; s++) {
            int lr = s * 8 + rl;  // 0..31
            int row = pass * 32 + lr;
            int chunk = c8 ^ (lr & 7);
            uint4 v = *(const uint4*)(eb + lr * 64 + chunk * 8);
            size_t ga = (size_t)(m0 + wm + row) * CH + wn + c8 * 8;
            if (resid) {
                uint4 h = *(const uint4*)(resid + ga);
                uint res[4];
                const uint* vp = (const uint*)&v;
                const uint* hp = (const uint*)&h;
                #pragma unroll
                for (int w = 0; w < 4; w++) {
                    float y0 = bf2f((ushort)(vp[w] & 0xffff));
                    float y1 = bf2f((ushort)(vp[w] >> 16));
                    float h0 = bf2f((ushort)(hp[w] & 0xffff));
                    float h1 = bf2f((ushort)(hp[w] >> 16));
                    res[w] = (uint)f2bf((h0 + y0) * 0.5f) | ((uint)f2bf((h1 + y1) * 0.5f) << 16);
                }
                v = *(uint4*)res;
            }
            *(uint4*)(outb + ga) = v;
        }
    }
}

// ---------------- fused lin GEMM: C[M][256] = bf16(X[M][963] zero-pad 1024) @ Wt^T + bias --
// SEPARATE kernel (own regalloc — extra f32 staging regs must not perturb gemm_bf16).
// A staged via coalesced f32 loads + f2bf (identical rounding to old pad_x) + ds_write_b128
// into the SAME swizzled layout; B via global_load_lds. Eliminates the 328 MB xp roundtrip.

__global__ __launch_bounds__(512, 4) void gemm_lin(const float* __restrict__ X,
                                                   const ushort* __restrict__ Wt,
                                                   const float* __restrict__ bias,
                                                   ushort* __restrict__ outb) {
    const int K = 1024, KX = 963;
    __shared__ __align__(16) ushort smem[24576];
    ushort* As = smem;
    ushort* Bs = smem + 128 * 64;
    int t = threadIdx.x;
    int lane = t & 63, wv = t >> 6;
    int m0 = blockIdx.x * BM;
    int lm = lane & 15, quad = lane >> 4;
    int wm = (wv >> 2) * 64;
    int wn = (wv & 3) * 64;

    int srow = t >> 3, sch = t & 7;
    int gch = sch ^ (srow & 7);

    const float* xP[2];
    ushort* aL[2];
    #pragma unroll
    for (int p = 0; p < 2; p++) {
        int row = p * 64 + srow;
        xP[p] = X + (size_t)(m0 + row) * KX;   // f32 row, length 963
        aL[p] = As + (p * 512 + t) * 8;
    }
    const ushort* bP[4];
    ushort* bL[4];
    #pragma unroll
    for (int p = 0; p < 4; p++) {
        int row = p * 64 + srow;
        bP[p] = Wt + (size_t)row * K + gch * 8;
        bL[p] = Bs + (p * 512 + t) * 8;
    }

    f32x4 acc[4][4];
    #pragma unroll
    for (int i = 0; i < 4; i++)
        #pragma unroll
        for (int j = 0; j < 4; j++) acc[i][j] = (f32x4){0.f, 0.f, 0.f, 0.f};

    for (int kt = 0; kt < K; kt += 64) {
        __syncthreads();
        // A: f32 load (coalesced: each thread 8 contiguous floats) + convert + LDS write
        #pragma unroll
        for (int p = 0; p < 2; p++) {
            int k0 = kt + gch * 8;
            ushort tb[8];
            if (k0 + 8 <= KX) {             // tiles 0..14 fully in-range (max k = 959 < 963)
                #pragma unroll
                for (int j = 0; j < 8; j++) tb[j] = f2bf(xP[p][k0 + j]);
            } else {                        // kt=960 boundary tile
                #pragma unroll
                for (int j = 0; j < 8; j++) {
                    int k = k0 + j;
                    tb[j] = (k < KX) ? f2bf(xP[p][k]) : (ushort)0;
                }
            }
            *(uint4*)aL[p] = *(const uint4*)tb;
        }
        #pragma unroll
        for (int p = 0; p < 4; p++)
            gload_lds16(bP[p] + kt, bL[p]);
        __syncthreads();  // drains lgkm (A writes) + vmcnt (B loads)
        #pragma unroll
        for (int ks = 0; ks < 2; ks++) {
            bf16x8_t af[4];
            #pragma unroll
            for (int i = 0; i < 4; i++) {
                int row = wm + i * 16 + lm;
                int chunk = (ks * 4 + quad) ^ (row & 7);
                af[i] = *(const bf16x8_t*)(As + row * 64 + chunk * 8);
            }
            #pragma unroll
            for (int j = 0; j < 4; j++) {
                int row = wn + j * 16 + lm;
                int chunk = (ks * 4 + quad) ^ (row & 7);
                bf16x8_t bfr = *(const bf16x8_t*)(Bs + row * 64 + chunk * 8);
                #pragma unroll
                for (int i = 0; i < 4; i++)
                    acc[i][j] = __builtin_amdgcn_mfma_f32_16x16x32_bf16(af[i], bfr, acc[i][j], 0, 0, 0);
            }
        }
    }

    // epilogue (no relu, no resid): two 32-row passes
    float bj[4];
    #pragma unroll
    for (int j = 0; j < 4; j++) bj[j] = bias[wn + j * 16 + lm];
    int rl = lane >> 3, c8 = lane & 7;
    ushort* eb = smem + wv * 2048;
    #pragma unroll
    for (int pass = 0; pass < 2; pass++) {
        __syncthreads();
        #pragma unroll
        for (int ih = 0; ih < 2; ih++) {
            int i = pass * 2 + ih;
            #pragma unroll
            for (int r = 0; r < 4; r++) {
                int lr = ih * 16 + quad * 4 + r;
                int sw = lr & 7;
                #pragma unroll
                for (int j = 0; j < 4; j++) {
                    int col = j * 16 + lm;
                    int scol = ((((col >> 3) ^ sw)) << 3) | (col & 7);
                    eb[lr * 64 + scol] = f2bf(acc[i][j][r] + bj[j]);
                }
            }
        }
        #pragma unroll
        for (int s = 0; s < 4; s++) {
            int lr = s * 8 + rl;
            int row = pass * 32 + lr;
            int chunk = c8 ^ (lr & 7);
            uint4 v = *(const uint4*)(eb + lr * 64 + chunk * 8);
            size_t ga = (size_t)(m0 + wm + row) * CH + wn + c8 * 8;
            *(uint4*)(outb + ga) = v;
        }
    }
}

// ---------------- fused: h (bf16) -> output 0 (fp32)  AND  h @ W3 -> t3 ----------------

__global__ __launch_bounds__(256) void cvt3_kernel(const ushort* __restrict__ Hb,
                                                   const float* __restrict__ W3,
                                                   float* __restrict__ Hf,
                                                   float* __restrict__ t3) {
    int wv = threadIdx.x >> 6, lane = threadIdx.x & 63;
    int nd = blockIdx.x * 4 + wv;  // [0, BB*NN)
    uint2 hv = *(const uint2*)(Hb + (size_t)nd * CH + lane * 4);
    float hp[4];
    hp[0] = bf2f((ushort)(hv.x & 0xffff));
    hp[1] = bf2f((ushort)(hv.x >> 16));
    hp[2] = bf2f((ushort)(hv.y & 0xffff));
    hp[3] = bf2f((ushort)(hv.y >> 16));
    float4 o;
    o.x = hp[0]; o.y = hp[1]; o.z = hp[2]; o.w = hp[3];
    *(float4*)(Hf + (size_t)nd * CH + lane * 4) = o;
    int k0 = lane * 4;
    float s0 = 0.f, s1 = 0.f, s2 = 0.f;
    #pragma unroll
    for (int j = 0; j < 4; j++) {
        float h = hp[j];
        s0 += h * W3[(k0 + j) * 3 + 0];
        s1 += h * W3[(k0 + j) * 3 + 1];
        s2 += h * W3[(k0 + j) * 3 + 2];
    }
    #pragma unroll
    for (int off = 32; off; off >>= 1) {
        s0 += __shfl_down(s0, off, 64);
        s1 += __shfl_down(s1, off, 64);
        s2 += __shfl_down(s2, off, 64);
    }
    if (lane == 0) {
        t3[(size_t)nd * 3 + 0] = s0;
        t3[(size_t)nd * 3 + 1] = s1;
        t3[(size_t)nd * 3 + 2] = s2;
    }
}

__global__ __launch_bounds__(256) void agg3_kernel(const float* __restrict__ t3,
                                                   const float* __restrict__ bias,
                                                   const float* __restrict__ dinv,
                                                   const int* __restrict__ rowptr,
                                                   const int2* __restrict__ edgew,
                                                   float* __restrict__ out) {
    int i = blockIdx.x * 256 + threadIdx.x;
    if (i >= BB * NN) return;
    int b = i / NN, d = i - b * NN;
    const float* t3b = t3 + (size_t)b * NN * 3;
    int r0 = rowptr[(size_t)b * (NN + 1) + d];
    int r1 = rowptr[(size_t)b * (NN + 1) + d + 1];
    float dd = dinv[b * NN + d];
    float a0 = 0.f, a1 = 0.f, a2 = 0.f;
    const int2* cw = edgew + (size_t)b * EE;
    for (int j = r0; j < r1; j++) {
        int2 e = cw[j];
        float w = __int_as_float(e.y);
        a0 += w * t3b[e.x * 3 + 0];
        a1 += w * t3b[e.x * 3 + 1];
        a2 += w * t3b[e.x * 3 + 2];
    }
    float w = dd * dd;
    a0 += w * t3b[d * 3 + 0] + bias[0];
    a1 += w * t3b[d * 3 + 1] + bias[1];
    a2 += w * t3b[d * 3 + 2] + bias[2];
    size_t o = (size_t)i * 3;
    out[o + 0] = a0;
    out[o + 1] = a1;
    out[o + 2] = a2;
}

// ---------------- host ----------------

extern "C" void kernel_launch(void* const* d_in, const int* in_sizes, int n_in,
                              void* d_out, int out_size, void* d_ws, size_t ws_size,
                              hipStream_t stream) {
    const float* x     = (const float*)d_in[0];
    const int*   edge  = (const int*)d_in[1];
    const int*   symm  = (const int*)d_in[2];
    const float* linW  = (const float*)d_in[3];
    const float* linb  = (const float*)d_in[4];
    const float* c1W   = (const float*)d_in[5];
    const float* c1b   = (const float*)d_in[6];
    const float* blkW  = (const float*)d_in[7];
    const float* blkWs = (const float*)d_in[8];
    const float* blkb  = (const float*)d_in[9];
    const float* c3W   = (const float*)d_in[10];
    const float* c3b   = (const float*)d_in[11];

    char* ws = (char*)d_ws;
    size_t off = 0;
    auto alloc = [&](size_t bytes) -> void* {
        void* p = ws + off;
        off += (bytes + 255) & ~(size_t)255;
        return p;
    };
    ushort* us     = (ushort*)alloc((size_t)BB * NN * CH * 2);   // [B*N][256] bf16 (41 MB)
    ushort* Hb     = (ushort*)alloc((size_t)BB * NN * CH * 2);
    ushort* y      = (ushort*)alloc((size_t)BB * NN * CH * 2);
    float*  t3     = (float*) alloc((size_t)BB * NN * 3 * 4);
    ushort* linWt  = (ushort*)alloc((size_t)256 * 1024 * 2);
    ushort* c1Wt   = (ushort*)alloc((size_t)256 * 256 * 2);
    ushort* blkWc  = (ushort*)alloc((size_t)12 * 256 * 512 * 2);
    int*    cnt    = (int*)  alloc((size_t)BB * NN * 4);
    int*    fill   = (int*)  alloc((size_t)BB * NN * 4);
    float*  dinv   = (float*)alloc((size_t)BB * NN * 4);
    int*    rowptr = (int*)  alloc((size_t)BB * (NN + 1) * 4);
    int2*   edgew  = (int2*) alloc((size_t)BB * EE * 8);
    int*    symg   = (int*)  alloc((size_t)BB * NN * 4);

    float* Hf   = (float*)d_out;                  // [B,N,256] float (output 0 = final h)
    float* out2 = Hf + (size_t)BB * NN * CH;      // [B,N,3] float (output 1)

    // CSR + norm
    init_zero_kernel<<<(BB * NN + 255) / 256, 256, 0, stream>>>(cnt, fill);
    count_kernel<<<(BB * EE + 255) / 256, 256, 0, stream>>>(edge, cnt);
    dinv_kernel<<<(BB * NN + 255) / 256, 256, 0, stream>>>(cnt, dinv);
    symg_kernel<<<(BB * NN + 255) / 256, 256, 0, stream>>>(symm, symg);
    scan_kernel<<<BB, 256, 0, stream>>>(cnt, rowptr);
    fill_kernel<<<(BB * EE + 255) / 256, 256, 0, stream>>>(edge, rowptr, dinv, fill, edgew);

    // weight conversion/transpose (float -> bf16)
    wt_lin_kernel<<<(256 * 1024 + 255) / 256, 256, 0, stream>>>(linW, linWt);
    wt_sq_kernel<<<(65536 + 255) / 256, 256, 0, stream>>>(c1W, c1Wt);
    wt_cat_kernel<<<(12 * 256 * 512 + 255) / 256, 256, 0, stream>>>(blkW, blkWs, blkWc);

    int ggrid = (BB * NN) / BM;     // 625 blocks, full N=256 per block
    dim3 agrid(NN / 8, BB);         // 2500 x 4, 8 nodes/block (half-wave each)

    // lin: fused f32->bf16 conversion inside the GEMM (no xp materialization)
    gemm_lin<<<ggrid, 512, 0, stream>>>(x, linWt, linb, Hb);

    // conv1: u = P@x_lin; h = relu(u@c1W + c1b) -> Hb
    gather_kernel<<<agrid, 256, 0, stream>>>(Hb, dinv, rowptr, edgew, us);
    gemm_bf16<<<ggrid, 512, 0, stream>>>(us, 256, c1Wt, c1b, nullptr, nullptr, nullptr,
                                         Hb, BB * NN, 256, 1);

    // 6 GBottleneck blocks: y = relu([P@h|h[symm]]@Wc0 + b0);
    //                       h = (h + relu([P@y|y[symm]]@Wc1 + b1)) * 0.5
    // symm half read directly inside the GEMM (hsym + symg), never materialized.
    for (int i = 0; i < 6; i++) {
        const ushort* Wc0 = blkWc + (size_t)(2 * i) * 131072;
        const float*  b0  = blkb  + (size_t)(2 * i) * 256;
        const ushort* Wc1 = blkWc + (size_t)(2 * i + 1) * 131072;
        const float*  b1  = blkb  + (size_t)(2 * i + 1) * 256;

        gather_kernel<<<agrid, 256, 0, stream>>>(Hb, dinv, rowptr, edgew, us);
        gemm_bf16<<<ggrid, 512, 0, stream>>>(us, 256, Wc0, b0, nullptr, Hb, symg,
                                             y, BB * NN, 512, 1);

        gather_kernel<<<agrid, 256, 0, stream>>>(y, dinv, rowptr, edgew, us);
        gemm_bf16<<<ggrid, 512, 0, stream>>>(us, 256, Wc1, b1, Hb, y, symg,
                                             Hb, BB * NN, 512, 1);
    }

    // output 0 (h fp32) + conv3 projection, single pass over Hb
    cvt3_kernel<<<(BB * NN) / 4, 256, 0, stream>>>(Hb, c3W, Hf, t3);
    agg3_kernel<<<(BB * NN + 255) / 256, 256, 0, stream>>>(t3, c3b, dinv,
                                                           rowptr, edgew, out2);

    (void)in_sizes; (void)n_in; (void)out_size; (void)ws_size;
}